// Round 2
// baseline (4138.093 us; speedup 1.0000x reference)
//
#include <hip/hip_runtime.h>
#include <hip/hip_bf16.h>

#define TPB 256

__global__ void k_init(int* __restrict__ deg, float* __restrict__ sums, int n){
  int i = blockIdx.x*TPB + threadIdx.x;
  if(i < n) deg[i] = 0;
  if(i < 2) sums[i] = 0.f;
}

__global__ void k_deg(const int* __restrict__ dst, int E, int* __restrict__ deg){
  int e = blockIdx.x*TPB + threadIdx.x;
  if(e < E) atomicAdd(&deg[dst[e]], 1);
}

__global__ void k_dinv(const int* __restrict__ deg, float* __restrict__ dinv, int n){
  int i = blockIdx.x*TPB + threadIdx.x;
  if(i < n) dinv[i] = rsqrtf((float)(deg[i] + 1));   // +1 = self loop; always >= 1
}

// gcn#1 layer1 prep: A-first on the scalar input (x*10). y = dinv*val, acc init = self-loop term.
__global__ void k_prep_first(const float* __restrict__ x, const float* __restrict__ dinv,
                             float* __restrict__ ys, float* __restrict__ accs, int n){
  int i = blockIdx.x*TPB + threadIdx.x;
  if(i < n){
    float u = dinv[i] * (10.f * x[i]);
    ys[i] = u; accs[i] = u;
  }
}

__global__ void k_scat1(const int* __restrict__ src, const int* __restrict__ dst, int E,
                        const float* __restrict__ ys, float* __restrict__ accs){
  int e = blockIdx.x*TPB + threadIdx.x;
  if(e < E) atomicAdd(&accs[dst[e]], ys[src[e]]);
}

// epilogue layer1 (scalar agg -> 4 feats, relu) fused with prep layer2 (A on 4 dims)
__global__ void k_l1_to_l2(const float* __restrict__ dinv, const float* __restrict__ accs,
                           const float* __restrict__ W1, const float* __restrict__ B1,
                           float* __restrict__ y4, float* __restrict__ acc4, int n){
  int i = blockIdx.x*TPB + threadIdx.x;
  if(i < n){
    float dv = dinv[i];
    float t  = dv * accs[i];                       // (A x10)[i]
    float h0 = fmaxf(t * W1[0] + B1[0], 0.f);
    float h1 = fmaxf(t * W1[1] + B1[1], 0.f);
    float h2 = fmaxf(t * W1[2] + B1[2], 0.f);
    float h3 = fmaxf(t * W1[3] + B1[3], 0.f);
    float4 u = make_float4(dv*h0, dv*h1, dv*h2, dv*h3);
    *reinterpret_cast<float4*>(y4  + 4*i) = u;
    *reinterpret_cast<float4*>(acc4 + 4*i) = u;    // self-loop init
  }
}

__global__ void k_scat4(const int* __restrict__ src, const int* __restrict__ dst, int E,
                        const float* __restrict__ y4, float* __restrict__ acc4){
  int e = blockIdx.x*TPB + threadIdx.x;
  if(e < E){
    int s = src[e], d = dst[e];
    float4 v = *reinterpret_cast<const float4*>(y4 + 4*s);
    float* base = acc4 + 4*d;
    atomicAdd(base+0, v.x);
    atomicAdd(base+1, v.y);
    atomicAdd(base+2, v.z);
    atomicAdd(base+3, v.w);
  }
}

// epilogue layer2 (4-dim agg -> relu(z@W2+b2)) fused with W-first layer3 (s = g.W3) prep
__global__ void k_l2_to_l3(const float* __restrict__ dinv, const float* __restrict__ acc4,
                           const float* __restrict__ W2, const float* __restrict__ B2,
                           const float* __restrict__ W3,
                           float* __restrict__ ys, float* __restrict__ accs, int n){
  int i = blockIdx.x*TPB + threadIdx.x;
  if(i < n){
    float dv = dinv[i];
    float4 a = *reinterpret_cast<const float4*>(acc4 + 4*i);
    float z0 = dv*a.x, z1 = dv*a.y, z2 = dv*a.z, z3 = dv*a.w;   // (A h)[i][:]
    float s = 0.f;
    #pragma unroll
    for(int k=0;k<4;k++){
      float g = B2[k];
      g += z0 * W2[0*4+k];
      g += z1 * W2[1*4+k];
      g += z2 * W2[2*4+k];
      g += z3 * W2[3*4+k];
      g = fmaxf(g, 0.f);
      s += g * W3[k];
    }
    float u = dv * s;
    ys[i] = u; accs[i] = u;
  }
}

// epilogue gcn#1 layer3: x2 = sin(10*(dv*acc + b3)); fused prep of gcn#2 layer1
__global__ void k_mid(const float* __restrict__ dinv, const float* __restrict__ B3,
                      float* __restrict__ x2, float* __restrict__ ys,
                      float* __restrict__ accs, int n){
  int i = blockIdx.x*TPB + threadIdx.x;
  if(i < n){
    float v  = dinv[i]*accs[i] + B3[0];
    float s2 = sinf(10.f * v);
    x2[i] = s2;
    float u = dinv[i] * s2;
    ys[i] = u; accs[i] = u;     // same index read->write, same thread: safe
  }
}

// epilogue gcn#2 layer3: x3; write node embeddings (f32, interleaved) + mean partials
__global__ void k_final(const float* __restrict__ dinv, const float* __restrict__ accs,
                        const float* __restrict__ B3, const float* __restrict__ x2,
                        float* __restrict__ out, float* __restrict__ sums, int n){
  int i = blockIdx.x*TPB + threadIdx.x;
  float sx2 = 0.f, sx3 = 0.f;
  if(i < n){
    float x3 = dinv[i]*accs[i] + B3[0];
    float v2 = x2[i];
    float2 pr = make_float2(v2, x3);
    *reinterpret_cast<float2*>(out + 2 + 2*(size_t)i) = pr;
    sx2 = v2; sx3 = x3;
  }
  #pragma unroll
  for(int off=32; off; off>>=1){
    sx2 += __shfl_down(sx2, off, 64);
    sx3 += __shfl_down(sx3, off, 64);
  }
  __shared__ float l2s[4], l3s[4];
  int lane = threadIdx.x & 63, w = threadIdx.x >> 6;
  if(lane == 0){ l2s[w] = sx2; l3s[w] = sx3; }
  __syncthreads();
  if(threadIdx.x == 0){
    atomicAdd(&sums[0], l2s[0]+l2s[1]+l2s[2]+l2s[3]);
    atomicAdd(&sums[1], l3s[0]+l3s[1]+l3s[2]+l3s[3]);
  }
}

__global__ void k_mean(const float* __restrict__ sums, float* __restrict__ out, float invn){
  if(threadIdx.x == 0){
    out[0] = sums[0] * invn;
    out[1] = sums[1] * invn;
  }
}

extern "C" void kernel_launch(void* const* d_in, const int* in_sizes, int n_in,
                              void* d_out, int out_size, void* d_ws, size_t ws_size,
                              hipStream_t stream) {
  const float* x   = (const float*)d_in[0];
  const int*   ei  = (const int*)  d_in[1];
  const float* w11 = (const float*)d_in[2];
  const float* b11 = (const float*)d_in[3];
  const float* w12 = (const float*)d_in[4];
  const float* b12 = (const float*)d_in[5];
  const float* w13 = (const float*)d_in[6];
  const float* b13 = (const float*)d_in[7];
  const float* w21 = (const float*)d_in[8];
  const float* b21 = (const float*)d_in[9];
  const float* w22 = (const float*)d_in[10];
  const float* b22 = (const float*)d_in[11];
  const float* w23 = (const float*)d_in[12];
  const float* b23 = (const float*)d_in[13];
  float* out = (float*)d_out;

  const int n = in_sizes[0];
  const int E = in_sizes[1] / 2;
  const int* src = ei;
  const int* dst = ei + E;

  float* ws   = (float*)d_ws;
  float* dinv = ws;              // n
  int*   deg  = (int*)(ws + n);  // n
  float* ys   = ws + 2*(size_t)n;       // n
  float* accs = ws + 3*(size_t)n;       // n
  float* y4   = ws + 4*(size_t)n;       // 4n
  float* acc4 = ws + 8*(size_t)n;       // 4n
  float* x2   = ws + 12*(size_t)n;      // n
  float* sums = ws + 13*(size_t)n;      // 2

  const int gn = (n + TPB - 1)/TPB;
  const int ge = (E + TPB - 1)/TPB;

  k_init<<<gn, TPB, 0, stream>>>(deg, sums, n);
  k_deg <<<ge, TPB, 0, stream>>>(dst, E, deg);
  k_dinv<<<gn, TPB, 0, stream>>>(deg, dinv, n);

  // ---- gcn3 #1 (input x*10) ----
  k_prep_first<<<gn, TPB, 0, stream>>>(x, dinv, ys, accs, n);
  k_scat1<<<ge, TPB, 0, stream>>>(src, dst, E, ys, accs);
  k_l1_to_l2<<<gn, TPB, 0, stream>>>(dinv, accs, w11, b11, y4, acc4, n);
  k_scat4<<<ge, TPB, 0, stream>>>(src, dst, E, y4, acc4);
  k_l2_to_l3<<<gn, TPB, 0, stream>>>(dinv, acc4, w12, b12, w13, ys, accs, n);
  k_scat1<<<ge, TPB, 0, stream>>>(src, dst, E, ys, accs);
  k_mid<<<gn, TPB, 0, stream>>>(dinv, b13, x2, ys, accs, n);

  // ---- gcn3 #2 (input x2) ----
  k_scat1<<<ge, TPB, 0, stream>>>(src, dst, E, ys, accs);
  k_l1_to_l2<<<gn, TPB, 0, stream>>>(dinv, accs, w21, b21, y4, acc4, n);
  k_scat4<<<ge, TPB, 0, stream>>>(src, dst, E, y4, acc4);
  k_l2_to_l3<<<gn, TPB, 0, stream>>>(dinv, acc4, w22, b22, w23, ys, accs, n);
  k_scat1<<<ge, TPB, 0, stream>>>(src, dst, E, ys, accs);
  k_final<<<gn, TPB, 0, stream>>>(dinv, accs, b23, x2, out, sums, n);
  k_mean<<<1, 64, 0, stream>>>(sums, out, 1.f/(float)n);
}

// Round 3
// 1628.969 us; speedup vs baseline: 2.5403x; 2.5403x over previous
//
#include <hip/hip_runtime.h>
#include <hip/hip_bf16.h>

#define TPB 256

// ============================ shared small kernels ============================

__global__ void k_init(int* __restrict__ deg, float* __restrict__ sums, int n){
  int i = blockIdx.x*TPB + threadIdx.x;
  if(i < n) deg[i] = 0;
  if(i < 2) sums[i] = 0.f;
}

__global__ void k_deg(const int* __restrict__ dst, int E, int* __restrict__ deg){
  int e = blockIdx.x*TPB + threadIdx.x;
  if(e < E) atomicAdd(&deg[dst[e]], 1);
}

__global__ void k_prep_first(const float* __restrict__ x, const float* __restrict__ dinv,
                             float* __restrict__ ys, int n){
  int i = blockIdx.x*TPB + threadIdx.x;
  if(i < n) ys[i] = dinv[i] * (10.f * x[i]);
}

__global__ void k_mean(const float* __restrict__ sums, float* __restrict__ out, float invn){
  if(threadIdx.x == 0){
    out[0] = sums[0] * invn;
    out[1] = sums[1] * invn;
  }
}

// ============================ CSR build ============================

// block sums of deg
__global__ void k_bsum(const int* __restrict__ deg, int n, int* __restrict__ bsum){
  int i = blockIdx.x*TPB + threadIdx.x;
  int v = (i < n) ? deg[i] : 0;
  #pragma unroll
  for(int off=32; off; off>>=1) v += __shfl_down(v, off, 64);
  __shared__ int ls[4];
  int lane = threadIdx.x & 63, w = threadIdx.x >> 6;
  if(lane == 0) ls[w] = v;
  __syncthreads();
  if(threadIdx.x == 0) bsum[blockIdx.x] = ls[0]+ls[1]+ls[2]+ls[3];
}

// single-block exclusive scan of block sums (nb <= 1024)
__global__ void k_bscan(int* __restrict__ bsum, int nb){
  __shared__ int s[1024];
  int t = threadIdx.x;
  int v = (t < nb) ? bsum[t] : 0;
  s[t] = v;
  __syncthreads();
  for(int off=1; off<1024; off<<=1){
    int add = (t >= off) ? s[t-off] : 0;
    __syncthreads();
    s[t] += add;
    __syncthreads();
  }
  if(t < nb) bsum[t] = s[t] - v;   // exclusive
}

// per-block exclusive scan of deg + block offset -> row_start, cursor; also dinv
__global__ void k_rowstart(const int* __restrict__ deg, const int* __restrict__ bsum, int n,
                           int* __restrict__ row_start, int* __restrict__ cursor,
                           float* __restrict__ dinv){
  __shared__ int s[TPB];
  int i = blockIdx.x*TPB + threadIdx.x;
  int t = threadIdx.x;
  int v = (i < n) ? deg[i] : 0;
  s[t] = v;
  __syncthreads();
  for(int off=1; off<TPB; off<<=1){
    int add = (t >= off) ? s[t-off] : 0;
    __syncthreads();
    s[t] += add;
    __syncthreads();
  }
  if(i < n){
    int rs = bsum[blockIdx.x] + s[t] - v;
    row_start[i] = rs;
    cursor[i]    = rs;
    dinv[i] = rsqrtf((float)(v + 1));   // +1 self loop, always >= 1
  }
}

__global__ void k_fill(const int* __restrict__ src, const int* __restrict__ dst, int E,
                       int* __restrict__ cursor, int* __restrict__ csr){
  int e = blockIdx.x*TPB + threadIdx.x;
  if(e < E){
    int d = dst[e];
    int pos = atomicAdd(&cursor[d], 1);
    csr[pos] = src[e];
  }
}

// ============================ fused gather layers ============================
// wave (64 lanes) per node; 4 nodes per 256-block

// layer1: scalar gather of ys -> t; epilogue (W1,B1, relu) -> y4 (dinv-premultiplied)
__global__ void k_gA(const int* __restrict__ csr, const int* __restrict__ row_start,
                     const int* __restrict__ deg, const float* __restrict__ dinv,
                     const float* __restrict__ ys, const float* __restrict__ W,
                     const float* __restrict__ B, float* __restrict__ y4, int n){
  int node = blockIdx.x*4 + (threadIdx.x >> 6);
  int lane = threadIdx.x & 63;
  if(node >= n) return;
  int rs = row_start[node], dg = deg[node];
  float s = 0.f;
  for(int j=lane; j<dg; j+=64) s += ys[csr[rs+j]];
  #pragma unroll
  for(int m=32; m; m>>=1) s += __shfl_xor(s, m, 64);
  if(lane == 0){
    float dv = dinv[node];
    float t  = dv * (ys[node] + s);
    float h0 = fmaxf(t*W[0]+B[0], 0.f);
    float h1 = fmaxf(t*W[1]+B[1], 0.f);
    float h2 = fmaxf(t*W[2]+B[2], 0.f);
    float h3 = fmaxf(t*W[3]+B[3], 0.f);
    *reinterpret_cast<float4*>(y4 + 4*(size_t)node) = make_float4(dv*h0, dv*h1, dv*h2, dv*h3);
  }
}

// layer2+3a: 4-vec gather of y4 -> z; epilogue (W2,B2 relu, dot W3) -> ys_out (dinv-premult)
__global__ void k_gB(const int* __restrict__ csr, const int* __restrict__ row_start,
                     const int* __restrict__ deg, const float* __restrict__ dinv,
                     const float* __restrict__ y4, const float* __restrict__ W2,
                     const float* __restrict__ B2, const float* __restrict__ W3,
                     float* __restrict__ ys_out, int n){
  int node = blockIdx.x*4 + (threadIdx.x >> 6);
  int lane = threadIdx.x & 63;
  if(node >= n) return;
  int rs = row_start[node], dg = deg[node];
  float ax=0.f, ay=0.f, az=0.f, aw=0.f;
  for(int j=lane; j<dg; j+=64){
    float4 v = *reinterpret_cast<const float4*>(y4 + 4*(size_t)csr[rs+j]);
    ax += v.x; ay += v.y; az += v.z; aw += v.w;
  }
  #pragma unroll
  for(int m=32; m; m>>=1){
    ax += __shfl_xor(ax, m, 64);
    ay += __shfl_xor(ay, m, 64);
    az += __shfl_xor(az, m, 64);
    aw += __shfl_xor(aw, m, 64);
  }
  if(lane == 0){
    float dv = dinv[node];
    float4 sf = *reinterpret_cast<const float4*>(y4 + 4*(size_t)node);
    float z0 = dv*(ax+sf.x), z1 = dv*(ay+sf.y), z2 = dv*(az+sf.z), z3 = dv*(aw+sf.w);
    float s = 0.f;
    #pragma unroll
    for(int k=0;k<4;k++){
      float g = B2[k] + z0*W2[0*4+k] + z1*W2[1*4+k] + z2*W2[2*4+k] + z3*W2[3*4+k];
      g = fmaxf(g, 0.f);
      s += g * W3[k];
    }
    ys_out[node] = dv * s;
  }
}

// gcn#1 layer3 finish: scalar gather of ys -> u; x2 = sin(10*(u+b3)); prep gcn#2 input
__global__ void k_gC_mid(const int* __restrict__ csr, const int* __restrict__ row_start,
                         const int* __restrict__ deg, const float* __restrict__ dinv,
                         const float* __restrict__ ys, const float* __restrict__ B3,
                         float* __restrict__ x2, float* __restrict__ ys_out, int n){
  int node = blockIdx.x*4 + (threadIdx.x >> 6);
  int lane = threadIdx.x & 63;
  if(node >= n) return;
  int rs = row_start[node], dg = deg[node];
  float s = 0.f;
  for(int j=lane; j<dg; j+=64) s += ys[csr[rs+j]];
  #pragma unroll
  for(int m=32; m; m>>=1) s += __shfl_xor(s, m, 64);
  if(lane == 0){
    float dv = dinv[node];
    float u  = dv * (ys[node] + s) + B3[0];
    float v2 = sinf(10.f * u);
    x2[node] = v2;
    ys_out[node] = dv * v2;
  }
}

// gcn#2 layer3 finish: x3; write node embeddings + mean partials
__global__ void k_gC_fin(const int* __restrict__ csr, const int* __restrict__ row_start,
                         const int* __restrict__ deg, const float* __restrict__ dinv,
                         const float* __restrict__ ys, const float* __restrict__ B3,
                         const float* __restrict__ x2, float* __restrict__ out,
                         float* __restrict__ sums, int n){
  int node = blockIdx.x*4 + (threadIdx.x >> 6);
  int lane = threadIdx.x & 63;
  int w = threadIdx.x >> 6;
  bool act = node < n;
  float v2 = 0.f, x3 = 0.f;
  if(act){
    int rs = row_start[node], dg = deg[node];
    float s = 0.f;
    for(int j=lane; j<dg; j+=64) s += ys[csr[rs+j]];
    #pragma unroll
    for(int m=32; m; m>>=1) s += __shfl_xor(s, m, 64);
    x3 = dinv[node] * (ys[node] + s) + B3[0];
    v2 = x2[node];
  }
  __shared__ float p2[4], p3[4];
  if(lane == 0){
    p2[w] = act ? v2 : 0.f;
    p3[w] = act ? x3 : 0.f;
    if(act)
      *reinterpret_cast<float2*>(out + 2 + 2*(size_t)node) = make_float2(v2, x3);
  }
  __syncthreads();
  if(threadIdx.x == 0){
    atomicAdd(&sums[0], p2[0]+p2[1]+p2[2]+p2[3]);
    atomicAdd(&sums[1], p3[0]+p3[1]+p3[2]+p3[3]);
  }
}

// ============================ fallback (atomic scatter, round-2 path) ============================

__global__ void k_dinv(const int* __restrict__ deg, float* __restrict__ dinv, int n){
  int i = blockIdx.x*TPB + threadIdx.x;
  if(i < n) dinv[i] = rsqrtf((float)(deg[i] + 1));
}

__global__ void k_prep_first2(const float* __restrict__ x, const float* __restrict__ dinv,
                              float* __restrict__ ys, float* __restrict__ accs, int n){
  int i = blockIdx.x*TPB + threadIdx.x;
  if(i < n){ float u = dinv[i]*(10.f*x[i]); ys[i]=u; accs[i]=u; }
}

__global__ void k_scat1(const int* __restrict__ src, const int* __restrict__ dst, int E,
                        const float* __restrict__ ys, float* __restrict__ accs){
  int e = blockIdx.x*TPB + threadIdx.x;
  if(e < E) atomicAdd(&accs[dst[e]], ys[src[e]]);
}

__global__ void k_l1_to_l2(const float* __restrict__ dinv, const float* __restrict__ accs,
                           const float* __restrict__ W1, const float* __restrict__ B1,
                           float* __restrict__ y4, float* __restrict__ acc4, int n){
  int i = blockIdx.x*TPB + threadIdx.x;
  if(i < n){
    float dv = dinv[i];
    float t  = dv * accs[i];
    float h0 = fmaxf(t*W1[0]+B1[0],0.f);
    float h1 = fmaxf(t*W1[1]+B1[1],0.f);
    float h2 = fmaxf(t*W1[2]+B1[2],0.f);
    float h3 = fmaxf(t*W1[3]+B1[3],0.f);
    float4 u = make_float4(dv*h0,dv*h1,dv*h2,dv*h3);
    *reinterpret_cast<float4*>(y4  + 4*(size_t)i) = u;
    *reinterpret_cast<float4*>(acc4 + 4*(size_t)i) = u;
  }
}

__global__ void k_scat4(const int* __restrict__ src, const int* __restrict__ dst, int E,
                        const float* __restrict__ y4, float* __restrict__ acc4){
  int e = blockIdx.x*TPB + threadIdx.x;
  if(e < E){
    int s = src[e], d = dst[e];
    float4 v = *reinterpret_cast<const float4*>(y4 + 4*(size_t)s);
    float* base = acc4 + 4*(size_t)d;
    atomicAdd(base+0, v.x); atomicAdd(base+1, v.y);
    atomicAdd(base+2, v.z); atomicAdd(base+3, v.w);
  }
}

__global__ void k_l2_to_l3(const float* __restrict__ dinv, const float* __restrict__ acc4,
                           const float* __restrict__ W2, const float* __restrict__ B2,
                           const float* __restrict__ W3,
                           float* __restrict__ ys, float* __restrict__ accs, int n){
  int i = blockIdx.x*TPB + threadIdx.x;
  if(i < n){
    float dv = dinv[i];
    float4 a = *reinterpret_cast<const float4*>(acc4 + 4*(size_t)i);
    float z0=dv*a.x, z1=dv*a.y, z2=dv*a.z, z3=dv*a.w;
    float s = 0.f;
    #pragma unroll
    for(int k=0;k<4;k++){
      float g = B2[k] + z0*W2[0*4+k] + z1*W2[1*4+k] + z2*W2[2*4+k] + z3*W2[3*4+k];
      g = fmaxf(g,0.f);
      s += g * W3[k];
    }
    float u = dv*s; ys[i]=u; accs[i]=u;
  }
}

__global__ void k_mid(const float* __restrict__ dinv, const float* __restrict__ B3,
                      float* __restrict__ x2, float* __restrict__ ys,
                      float* __restrict__ accs, int n){
  int i = blockIdx.x*TPB + threadIdx.x;
  if(i < n){
    float v = dinv[i]*accs[i] + B3[0];
    float s2 = sinf(10.f*v);
    x2[i]=s2;
    float u = dinv[i]*s2;
    ys[i]=u; accs[i]=u;
  }
}

__global__ void k_final(const float* __restrict__ dinv, const float* __restrict__ accs,
                        const float* __restrict__ B3, const float* __restrict__ x2,
                        float* __restrict__ out, float* __restrict__ sums, int n){
  int i = blockIdx.x*TPB + threadIdx.x;
  float sx2=0.f, sx3=0.f;
  if(i < n){
    float x3 = dinv[i]*accs[i] + B3[0];
    float v2 = x2[i];
    *reinterpret_cast<float2*>(out + 2 + 2*(size_t)i) = make_float2(v2, x3);
    sx2=v2; sx3=x3;
  }
  #pragma unroll
  for(int off=32; off; off>>=1){
    sx2 += __shfl_down(sx2, off, 64);
    sx3 += __shfl_down(sx3, off, 64);
  }
  __shared__ float l2s[4], l3s[4];
  int lane = threadIdx.x & 63, w = threadIdx.x >> 6;
  if(lane==0){ l2s[w]=sx2; l3s[w]=sx3; }
  __syncthreads();
  if(threadIdx.x==0){
    atomicAdd(&sums[0], l2s[0]+l2s[1]+l2s[2]+l2s[3]);
    atomicAdd(&sums[1], l3s[0]+l3s[1]+l3s[2]+l3s[3]);
  }
}

// ============================ launch ============================

extern "C" void kernel_launch(void* const* d_in, const int* in_sizes, int n_in,
                              void* d_out, int out_size, void* d_ws, size_t ws_size,
                              hipStream_t stream) {
  const float* x   = (const float*)d_in[0];
  const int*   ei  = (const int*)  d_in[1];
  const float* w11 = (const float*)d_in[2];
  const float* b11 = (const float*)d_in[3];
  const float* w12 = (const float*)d_in[4];
  const float* b12 = (const float*)d_in[5];
  const float* w13 = (const float*)d_in[6];
  const float* b13 = (const float*)d_in[7];
  const float* w21 = (const float*)d_in[8];
  const float* b21 = (const float*)d_in[9];
  const float* w22 = (const float*)d_in[10];
  const float* b22 = (const float*)d_in[11];
  const float* w23 = (const float*)d_in[12];
  const float* b23 = (const float*)d_in[13];
  float* out = (float*)d_out;

  const int n = in_sizes[0];
  const int E = in_sizes[1] / 2;
  const int* src = ei;
  const int* dst = ei + E;

  const int gn  = (n + TPB - 1)/TPB;     // node grid (thread per node)
  const int ge  = (E + TPB - 1)/TPB;     // edge grid
  const int gn4 = (n + 3)/4;             // wave-per-node grid (4 nodes / block)

  float* ws = (float*)d_ws;

  const size_t need = (size_t)(11*(size_t)n + 1028 + (size_t)E) * 4;
  if(ws_size >= need && gn <= 1024){
    // ---------------- CSR gather path ----------------
    float* y4        = ws;                         // 4n (16B aligned)
    float* dinv      = ws + 4*(size_t)n;           // n
    float* ysA       = ws + 5*(size_t)n;           // n
    float* ysB       = ws + 6*(size_t)n;           // n
    float* x2        = ws + 7*(size_t)n;           // n
    float* sums      = ws + 8*(size_t)n;           // 2 (pad to 4)
    int*   deg       = (int*)(ws + 8*(size_t)n + 4);   // n
    int*   row_start = (int*)(ws + 9*(size_t)n + 4);   // n
    int*   cursor    = (int*)(ws + 10*(size_t)n + 4);  // n
    int*   bsum      = (int*)(ws + 11*(size_t)n + 4);  // 1024
    int*   csr       = (int*)(ws + 11*(size_t)n + 1028); // E

    k_init    <<<gn, TPB, 0, stream>>>(deg, sums, n);
    k_deg     <<<ge, TPB, 0, stream>>>(dst, E, deg);
    k_bsum    <<<gn, TPB, 0, stream>>>(deg, n, bsum);
    k_bscan   <<<1, 1024, 0, stream>>>(bsum, gn);
    k_rowstart<<<gn, TPB, 0, stream>>>(deg, bsum, n, row_start, cursor, dinv);
    k_fill    <<<ge, TPB, 0, stream>>>(src, dst, E, cursor, csr);

    // gcn #1
    k_prep_first<<<gn, TPB, 0, stream>>>(x, dinv, ysA, n);
    k_gA    <<<gn4, TPB, 0, stream>>>(csr, row_start, deg, dinv, ysA, w11, b11, y4, n);
    k_gB    <<<gn4, TPB, 0, stream>>>(csr, row_start, deg, dinv, y4, w12, b12, w13, ysB, n);
    k_gC_mid<<<gn4, TPB, 0, stream>>>(csr, row_start, deg, dinv, ysB, b13, x2, ysA, n);
    // gcn #2
    k_gA    <<<gn4, TPB, 0, stream>>>(csr, row_start, deg, dinv, ysA, w21, b21, y4, n);
    k_gB    <<<gn4, TPB, 0, stream>>>(csr, row_start, deg, dinv, y4, w22, b22, w23, ysB, n);
    k_gC_fin<<<gn4, TPB, 0, stream>>>(csr, row_start, deg, dinv, ysB, b23, x2, out, sums, n);
    k_mean  <<<1, 64, 0, stream>>>(sums, out, 1.f/(float)n);
  } else {
    // ---------------- fallback: atomic scatter path ----------------
    float* dinv = ws;                     // n
    int*   deg  = (int*)(ws + n);         // n
    float* ys   = ws + 2*(size_t)n;       // n
    float* accs = ws + 3*(size_t)n;       // n
    float* y4   = ws + 4*(size_t)n;       // 4n
    float* acc4 = ws + 8*(size_t)n;       // 4n
    float* x2   = ws + 12*(size_t)n;      // n
    float* sums = ws + 13*(size_t)n;      // 2

    k_init<<<gn, TPB, 0, stream>>>(deg, sums, n);
    k_deg <<<ge, TPB, 0, stream>>>(dst, E, deg);
    k_dinv<<<gn, TPB, 0, stream>>>(deg, dinv, n);

    k_prep_first2<<<gn, TPB, 0, stream>>>(x, dinv, ys, accs, n);
    k_scat1<<<ge, TPB, 0, stream>>>(src, dst, E, ys, accs);
    k_l1_to_l2<<<gn, TPB, 0, stream>>>(dinv, accs, w11, b11, y4, acc4, n);
    k_scat4<<<ge, TPB, 0, stream>>>(src, dst, E, y4, acc4);
    k_l2_to_l3<<<gn, TPB, 0, stream>>>(dinv, acc4, w12, b12, w13, ys, accs, n);
    k_scat1<<<ge, TPB, 0, stream>>>(src, dst, E, ys, accs);
    k_mid<<<gn, TPB, 0, stream>>>(dinv, b13, x2, ys, accs, n);

    k_scat1<<<ge, TPB, 0, stream>>>(src, dst, E, ys, accs);
    k_l1_to_l2<<<gn, TPB, 0, stream>>>(dinv, accs, w21, b21, y4, acc4, n);
    k_scat4<<<ge, TPB, 0, stream>>>(src, dst, E, y4, acc4);
    k_l2_to_l3<<<gn, TPB, 0, stream>>>(dinv, acc4, w22, b22, w23, ys, accs, n);
    k_scat1<<<ge, TPB, 0, stream>>>(src, dst, E, ys, accs);
    k_final<<<gn, TPB, 0, stream>>>(dinv, accs, b23, x2, out, sums, n);
    k_mean<<<1, 64, 0, stream>>>(sums, out, 1.f/(float)n);
  }
}

// Round 4
// 1048.031 us; speedup vs baseline: 3.9484x; 1.5543x over previous
//
#include <hip/hip_runtime.h>
#include <hip/hip_bf16.h>

#define TPB 256
#define NSHADOW 8

// ============================ small kernels ============================

__global__ void k_zero8(int* __restrict__ degS, int m){   // m = 8n
  int i = blockIdx.x*TPB + threadIdx.x;
  if(i < m) degS[i] = 0;
}

// 8-way shadowed degree histogram: contention /8 on each address
__global__ void k_deg8(const int* __restrict__ dst, int E, int* __restrict__ degS, int n){
  int e = blockIdx.x*TPB + threadIdx.x;
  if(e < E) atomicAdd(&degS[(size_t)(blockIdx.x & (NSHADOW-1))*(size_t)n + dst[e]], 1);
}

__global__ void k_prep_first(const float* __restrict__ x, const float* __restrict__ dinv,
                             float* __restrict__ ys, int n){
  int i = blockIdx.x*TPB + threadIdx.x;
  if(i < n) ys[i] = dinv[i] * (10.f * x[i]);
}

// final reduction of per-block partials -> mean
__global__ void k_reduce_mean(const float* __restrict__ pbuf, int nb,
                              float* __restrict__ out, float invn){
  float s2 = 0.f, s3 = 0.f;
  for(int i = threadIdx.x; i < nb; i += 1024){
    s2 += pbuf[2*i];
    s3 += pbuf[2*i+1];
  }
  #pragma unroll
  for(int m=32; m; m>>=1){ s2 += __shfl_xor(s2, m, 64); s3 += __shfl_xor(s3, m, 64); }
  __shared__ float a2[16], a3[16];
  int w = threadIdx.x >> 6, lane = threadIdx.x & 63;
  if(lane == 0){ a2[w] = s2; a3[w] = s3; }
  __syncthreads();
  if(threadIdx.x == 0){
    float t2 = 0.f, t3 = 0.f;
    #pragma unroll
    for(int k=0;k<16;k++){ t2 += a2[k]; t3 += a3[k]; }
    out[0] = t2 * invn;
    out[1] = t3 * invn;
  }
}

// ============================ CSR build ============================

// block sums of deg (deg = summed total)
__global__ void k_bsum(const int* __restrict__ degS, int n, int* __restrict__ bsum){
  int i = blockIdx.x*TPB + threadIdx.x;
  int v = 0;
  if(i < n){
    #pragma unroll
    for(int s=0;s<NSHADOW;s++) v += degS[(size_t)s*(size_t)n + i];
  }
  #pragma unroll
  for(int off=32; off; off>>=1) v += __shfl_down(v, off, 64);
  __shared__ int ls[4];
  int lane = threadIdx.x & 63, w = threadIdx.x >> 6;
  if(lane == 0) ls[w] = v;
  __syncthreads();
  if(threadIdx.x == 0) bsum[blockIdx.x] = ls[0]+ls[1]+ls[2]+ls[3];
}

// single-block exclusive scan of block sums (nb <= 1024)
__global__ void k_bscan(int* __restrict__ bsum, int nb){
  __shared__ int s[1024];
  int t = threadIdx.x;
  int v = (t < nb) ? bsum[t] : 0;
  s[t] = v;
  __syncthreads();
  for(int off=1; off<1024; off<<=1){
    int add = (t >= off) ? s[t-off] : 0;
    __syncthreads();
    s[t] += add;
    __syncthreads();
  }
  if(t < nb) bsum[t] = s[t] - v;   // exclusive
}

// per-block exclusive scan of deg + block offset -> deg, row_start, cursor, dinv
__global__ void k_rowstart(const int* __restrict__ degS, const int* __restrict__ bsum, int n,
                           int* __restrict__ deg, int* __restrict__ row_start,
                           int* __restrict__ cursor, float* __restrict__ dinv){
  __shared__ int s[TPB];
  int i = blockIdx.x*TPB + threadIdx.x;
  int t = threadIdx.x;
  int v = 0;
  if(i < n){
    #pragma unroll
    for(int sh=0;sh<NSHADOW;sh++) v += degS[(size_t)sh*(size_t)n + i];
  }
  s[t] = v;
  __syncthreads();
  for(int off=1; off<TPB; off<<=1){
    int add = (t >= off) ? s[t-off] : 0;
    __syncthreads();
    s[t] += add;
    __syncthreads();
  }
  if(i < n){
    int rs = bsum[blockIdx.x] + s[t] - v;
    deg[i]       = v;
    row_start[i] = rs;
    cursor[i]    = rs;
    dinv[i] = rsqrtf((float)(v + 1));   // +1 self loop, always >= 1
  }
}

__global__ void k_fill(const int* __restrict__ src, const int* __restrict__ dst, int E,
                       int* __restrict__ cursor, int* __restrict__ csr){
  int e = blockIdx.x*TPB + threadIdx.x;
  if(e < E){
    int d = dst[e];
    int pos = atomicAdd(&cursor[d], 1);
    csr[pos] = src[e];
  }
}

// ============================ fused gather layers ============================
// wave (64 lanes) per node; 4 nodes per 256-block

__global__ void k_gA(const int* __restrict__ csr, const int* __restrict__ row_start,
                     const int* __restrict__ deg, const float* __restrict__ dinv,
                     const float* __restrict__ ys, const float* __restrict__ W,
                     const float* __restrict__ B, float* __restrict__ y4, int n){
  int node = blockIdx.x*4 + (threadIdx.x >> 6);
  int lane = threadIdx.x & 63;
  if(node >= n) return;
  int rs = row_start[node], dg = deg[node];
  float s = 0.f;
  for(int j=lane; j<dg; j+=64) s += ys[csr[rs+j]];
  #pragma unroll
  for(int m=32; m; m>>=1) s += __shfl_xor(s, m, 64);
  if(lane == 0){
    float dv = dinv[node];
    float t  = dv * (ys[node] + s);
    float h0 = fmaxf(t*W[0]+B[0], 0.f);
    float h1 = fmaxf(t*W[1]+B[1], 0.f);
    float h2 = fmaxf(t*W[2]+B[2], 0.f);
    float h3 = fmaxf(t*W[3]+B[3], 0.f);
    *reinterpret_cast<float4*>(y4 + 4*(size_t)node) = make_float4(dv*h0, dv*h1, dv*h2, dv*h3);
  }
}

__global__ void k_gB(const int* __restrict__ csr, const int* __restrict__ row_start,
                     const int* __restrict__ deg, const float* __restrict__ dinv,
                     const float* __restrict__ y4, const float* __restrict__ W2,
                     const float* __restrict__ B2, const float* __restrict__ W3,
                     float* __restrict__ ys_out, int n){
  int node = blockIdx.x*4 + (threadIdx.x >> 6);
  int lane = threadIdx.x & 63;
  if(node >= n) return;
  int rs = row_start[node], dg = deg[node];
  float ax=0.f, ay=0.f, az=0.f, aw=0.f;
  for(int j=lane; j<dg; j+=64){
    float4 v = *reinterpret_cast<const float4*>(y4 + 4*(size_t)csr[rs+j]);
    ax += v.x; ay += v.y; az += v.z; aw += v.w;
  }
  #pragma unroll
  for(int m=32; m; m>>=1){
    ax += __shfl_xor(ax, m, 64);
    ay += __shfl_xor(ay, m, 64);
    az += __shfl_xor(az, m, 64);
    aw += __shfl_xor(aw, m, 64);
  }
  if(lane == 0){
    float dv = dinv[node];
    float4 sf = *reinterpret_cast<const float4*>(y4 + 4*(size_t)node);
    float z0 = dv*(ax+sf.x), z1 = dv*(ay+sf.y), z2 = dv*(az+sf.z), z3 = dv*(aw+sf.w);
    float s = 0.f;
    #pragma unroll
    for(int k=0;k<4;k++){
      float g = B2[k] + z0*W2[0*4+k] + z1*W2[1*4+k] + z2*W2[2*4+k] + z3*W2[3*4+k];
      g = fmaxf(g, 0.f);
      s += g * W3[k];
    }
    ys_out[node] = dv * s;
  }
}

__global__ void k_gC_mid(const int* __restrict__ csr, const int* __restrict__ row_start,
                         const int* __restrict__ deg, const float* __restrict__ dinv,
                         const float* __restrict__ ys, const float* __restrict__ B3,
                         float* __restrict__ x2, float* __restrict__ ys_out, int n){
  int node = blockIdx.x*4 + (threadIdx.x >> 6);
  int lane = threadIdx.x & 63;
  if(node >= n) return;
  int rs = row_start[node], dg = deg[node];
  float s = 0.f;
  for(int j=lane; j<dg; j+=64) s += ys[csr[rs+j]];
  #pragma unroll
  for(int m=32; m; m>>=1) s += __shfl_xor(s, m, 64);
  if(lane == 0){
    float dv = dinv[node];
    float u  = dv * (ys[node] + s) + B3[0];
    float v2 = sinf(10.f * u);
    x2[node] = v2;
    ys_out[node] = dv * v2;
  }
}

// gcn#2 layer3 finish: x3; write node embeddings + per-block partial sums (NO same-address atomics)
__global__ void k_gC_fin(const int* __restrict__ csr, const int* __restrict__ row_start,
                         const int* __restrict__ deg, const float* __restrict__ dinv,
                         const float* __restrict__ ys, const float* __restrict__ B3,
                         const float* __restrict__ x2, float* __restrict__ out,
                         float* __restrict__ pbuf, int n){
  int node = blockIdx.x*4 + (threadIdx.x >> 6);
  int lane = threadIdx.x & 63;
  int w = threadIdx.x >> 6;
  bool act = node < n;
  float v2 = 0.f, x3 = 0.f;
  if(act){
    int rs = row_start[node], dg = deg[node];
    float s = 0.f;
    for(int j=lane; j<dg; j+=64) s += ys[csr[rs+j]];
    #pragma unroll
    for(int m=32; m; m>>=1) s += __shfl_xor(s, m, 64);
    x3 = dinv[node] * (ys[node] + s) + B3[0];
    v2 = x2[node];
  }
  __shared__ float p2[4], p3[4];
  if(lane == 0){
    p2[w] = act ? v2 : 0.f;
    p3[w] = act ? x3 : 0.f;
    if(act)
      *reinterpret_cast<float2*>(out + 2 + 2*(size_t)node) = make_float2(v2, x3);
  }
  __syncthreads();
  if(threadIdx.x == 0){
    pbuf[2*(size_t)blockIdx.x]   = p2[0]+p2[1]+p2[2]+p2[3];
    pbuf[2*(size_t)blockIdx.x+1] = p3[0]+p3[1]+p3[2]+p3[3];
  }
}

// ============================ fallback (atomic scatter, round-2 path) ============================

__global__ void k_init(int* __restrict__ deg, float* __restrict__ sums, int n){
  int i = blockIdx.x*TPB + threadIdx.x;
  if(i < n) deg[i] = 0;
  if(i < 2) sums[i] = 0.f;
}

__global__ void k_deg(const int* __restrict__ dst, int E, int* __restrict__ deg){
  int e = blockIdx.x*TPB + threadIdx.x;
  if(e < E) atomicAdd(&deg[dst[e]], 1);
}

__global__ void k_dinv(const int* __restrict__ deg, float* __restrict__ dinv, int n){
  int i = blockIdx.x*TPB + threadIdx.x;
  if(i < n) dinv[i] = rsqrtf((float)(deg[i] + 1));
}

__global__ void k_prep_first2(const float* __restrict__ x, const float* __restrict__ dinv,
                              float* __restrict__ ys, float* __restrict__ accs, int n){
  int i = blockIdx.x*TPB + threadIdx.x;
  if(i < n){ float u = dinv[i]*(10.f*x[i]); ys[i]=u; accs[i]=u; }
}

__global__ void k_scat1(const int* __restrict__ src, const int* __restrict__ dst, int E,
                        const float* __restrict__ ys, float* __restrict__ accs){
  int e = blockIdx.x*TPB + threadIdx.x;
  if(e < E) atomicAdd(&accs[dst[e]], ys[src[e]]);
}

__global__ void k_l1_to_l2(const float* __restrict__ dinv, const float* __restrict__ accs,
                           const float* __restrict__ W1, const float* __restrict__ B1,
                           float* __restrict__ y4, float* __restrict__ acc4, int n){
  int i = blockIdx.x*TPB + threadIdx.x;
  if(i < n){
    float dv = dinv[i];
    float t  = dv * accs[i];
    float h0 = fmaxf(t*W1[0]+B1[0],0.f);
    float h1 = fmaxf(t*W1[1]+B1[1],0.f);
    float h2 = fmaxf(t*W1[2]+B1[2],0.f);
    float h3 = fmaxf(t*W1[3]+B1[3],0.f);
    float4 u = make_float4(dv*h0,dv*h1,dv*h2,dv*h3);
    *reinterpret_cast<float4*>(y4  + 4*(size_t)i) = u;
    *reinterpret_cast<float4*>(acc4 + 4*(size_t)i) = u;
  }
}

__global__ void k_scat4(const int* __restrict__ src, const int* __restrict__ dst, int E,
                        const float* __restrict__ y4, float* __restrict__ acc4){
  int e = blockIdx.x*TPB + threadIdx.x;
  if(e < E){
    int s = src[e], d = dst[e];
    float4 v = *reinterpret_cast<const float4*>(y4 + 4*(size_t)s);
    float* base = acc4 + 4*(size_t)d;
    atomicAdd(base+0, v.x); atomicAdd(base+1, v.y);
    atomicAdd(base+2, v.z); atomicAdd(base+3, v.w);
  }
}

__global__ void k_l2_to_l3(const float* __restrict__ dinv, const float* __restrict__ acc4,
                           const float* __restrict__ W2, const float* __restrict__ B2,
                           const float* __restrict__ W3,
                           float* __restrict__ ys, float* __restrict__ accs, int n){
  int i = blockIdx.x*TPB + threadIdx.x;
  if(i < n){
    float dv = dinv[i];
    float4 a = *reinterpret_cast<const float4*>(acc4 + 4*(size_t)i);
    float z0=dv*a.x, z1=dv*a.y, z2=dv*a.z, z3=dv*a.w;
    float s = 0.f;
    #pragma unroll
    for(int k=0;k<4;k++){
      float g = B2[k] + z0*W2[0*4+k] + z1*W2[1*4+k] + z2*W2[2*4+k] + z3*W2[3*4+k];
      g = fmaxf(g,0.f);
      s += g * W3[k];
    }
    float u = dv*s; ys[i]=u; accs[i]=u;
  }
}

__global__ void k_mid(const float* __restrict__ dinv, const float* __restrict__ B3,
                      float* __restrict__ x2, float* __restrict__ ys,
                      float* __restrict__ accs, int n){
  int i = blockIdx.x*TPB + threadIdx.x;
  if(i < n){
    float v = dinv[i]*accs[i] + B3[0];
    float s2 = sinf(10.f*v);
    x2[i]=s2;
    float u = dinv[i]*s2;
    ys[i]=u; accs[i]=u;
  }
}

__global__ void k_final(const float* __restrict__ dinv, const float* __restrict__ accs,
                        const float* __restrict__ B3, const float* __restrict__ x2,
                        float* __restrict__ out, float* __restrict__ sums, int n){
  int i = blockIdx.x*TPB + threadIdx.x;
  float sx2=0.f, sx3=0.f;
  if(i < n){
    float x3 = dinv[i]*accs[i] + B3[0];
    float v2 = x2[i];
    *reinterpret_cast<float2*>(out + 2 + 2*(size_t)i) = make_float2(v2, x3);
    sx2=v2; sx3=x3;
  }
  #pragma unroll
  for(int off=32; off; off>>=1){
    sx2 += __shfl_down(sx2, off, 64);
    sx3 += __shfl_down(sx3, off, 64);
  }
  __shared__ float l2s[4], l3s[4];
  int lane = threadIdx.x & 63, w = threadIdx.x >> 6;
  if(lane==0){ l2s[w]=sx2; l3s[w]=sx3; }
  __syncthreads();
  if(threadIdx.x==0){
    atomicAdd(&sums[0], l2s[0]+l2s[1]+l2s[2]+l2s[3]);
    atomicAdd(&sums[1], l3s[0]+l3s[1]+l3s[2]+l3s[3]);
  }
}

__global__ void k_mean(const float* __restrict__ sums, float* __restrict__ out, float invn){
  if(threadIdx.x == 0){
    out[0] = sums[0] * invn;
    out[1] = sums[1] * invn;
  }
}

// ============================ launch ============================

extern "C" void kernel_launch(void* const* d_in, const int* in_sizes, int n_in,
                              void* d_out, int out_size, void* d_ws, size_t ws_size,
                              hipStream_t stream) {
  const float* x   = (const float*)d_in[0];
  const int*   ei  = (const int*)  d_in[1];
  const float* w11 = (const float*)d_in[2];
  const float* b11 = (const float*)d_in[3];
  const float* w12 = (const float*)d_in[4];
  const float* b12 = (const float*)d_in[5];
  const float* w13 = (const float*)d_in[6];
  const float* b13 = (const float*)d_in[7];
  const float* w21 = (const float*)d_in[8];
  const float* b21 = (const float*)d_in[9];
  const float* w22 = (const float*)d_in[10];
  const float* b22 = (const float*)d_in[11];
  const float* w23 = (const float*)d_in[12];
  const float* b23 = (const float*)d_in[13];
  float* out = (float*)d_out;

  const int n = in_sizes[0];
  const int E = in_sizes[1] / 2;
  const int* src = ei;
  const int* dst = ei + E;

  const int gn  = (n + TPB - 1)/TPB;
  const int ge  = (E + TPB - 1)/TPB;
  const int gn4 = (n + 3)/4;

  float* ws = (float*)d_ws;

  const size_t need = (size_t)(11*(size_t)n + 1024 + (size_t)E) * 4;
  if(ws_size >= need && gn <= 1024 && (size_t)E >= (size_t)NSHADOW*(size_t)n){
    // ---------------- CSR gather path ----------------
    float* y4        = ws;                           // 4n; later aliased as pbuf (2*gn4)
    float* dinv      = ws + 4*(size_t)n;             // n
    float* ysA       = ws + 5*(size_t)n;             // n
    float* ysB       = ws + 6*(size_t)n;             // n
    float* x2        = ws + 7*(size_t)n;             // n
    int*   deg       = (int*)(ws + 8*(size_t)n);     // n
    int*   row_start = (int*)(ws + 9*(size_t)n);     // n
    int*   cursor    = (int*)(ws + 10*(size_t)n);    // n
    int*   bsum      = (int*)(ws + 11*(size_t)n);    // 1024
    int*   csr       = (int*)(ws + 11*(size_t)n + 1024); // E; head 8n ints = degS during build
    int*   degS      = csr;                          // alias, dead before k_fill writes csr
    float* pbuf      = y4;                           // alias, y4 dead before k_gC_fin

    const int m8  = NSHADOW*n;
    k_zero8   <<<(m8+TPB-1)/TPB, TPB, 0, stream>>>(degS, m8);
    k_deg8    <<<ge, TPB, 0, stream>>>(dst, E, degS, n);
    k_bsum    <<<gn, TPB, 0, stream>>>(degS, n, bsum);
    k_bscan   <<<1, 1024, 0, stream>>>(bsum, gn);
    k_rowstart<<<gn, TPB, 0, stream>>>(degS, bsum, n, deg, row_start, cursor, dinv);
    k_fill    <<<ge, TPB, 0, stream>>>(src, dst, E, cursor, csr);

    // gcn #1
    k_prep_first<<<gn, TPB, 0, stream>>>(x, dinv, ysA, n);
    k_gA    <<<gn4, TPB, 0, stream>>>(csr, row_start, deg, dinv, ysA, w11, b11, y4, n);
    k_gB    <<<gn4, TPB, 0, stream>>>(csr, row_start, deg, dinv, y4, w12, b12, w13, ysB, n);
    k_gC_mid<<<gn4, TPB, 0, stream>>>(csr, row_start, deg, dinv, ysB, b13, x2, ysA, n);
    // gcn #2
    k_gA    <<<gn4, TPB, 0, stream>>>(csr, row_start, deg, dinv, ysA, w21, b21, y4, n);
    k_gB    <<<gn4, TPB, 0, stream>>>(csr, row_start, deg, dinv, y4, w22, b22, w23, ysB, n);
    k_gC_fin<<<gn4, TPB, 0, stream>>>(csr, row_start, deg, dinv, ysB, b23, x2, out, pbuf, n);
    k_reduce_mean<<<1, 1024, 0, stream>>>(pbuf, gn4, out, 1.f/(float)n);
  } else {
    // ---------------- fallback: atomic scatter path ----------------
    float* dinv = ws;                     // n
    int*   deg  = (int*)(ws + n);         // n
    float* ys   = ws + 2*(size_t)n;       // n
    float* accs = ws + 3*(size_t)n;       // n
    float* y4   = ws + 4*(size_t)n;       // 4n
    float* acc4 = ws + 8*(size_t)n;       // 4n
    float* x2   = ws + 12*(size_t)n;      // n
    float* sums = ws + 13*(size_t)n;      // 2

    k_init<<<gn, TPB, 0, stream>>>(deg, sums, n);
    k_deg <<<ge, TPB, 0, stream>>>(dst, E, deg);
    k_dinv<<<gn, TPB, 0, stream>>>(deg, dinv, n);

    k_prep_first2<<<gn, TPB, 0, stream>>>(x, dinv, ys, accs, n);
    k_scat1<<<ge, TPB, 0, stream>>>(src, dst, E, ys, accs);
    k_l1_to_l2<<<gn, TPB, 0, stream>>>(dinv, accs, w11, b11, y4, acc4, n);
    k_scat4<<<ge, TPB, 0, stream>>>(src, dst, E, y4, acc4);
    k_l2_to_l3<<<gn, TPB, 0, stream>>>(dinv, acc4, w12, b12, w13, ys, accs, n);
    k_scat1<<<ge, TPB, 0, stream>>>(src, dst, E, ys, accs);
    k_mid<<<gn, TPB, 0, stream>>>(dinv, b13, x2, ys, accs, n);

    k_scat1<<<ge, TPB, 0, stream>>>(src, dst, E, ys, accs);
    k_l1_to_l2<<<gn, TPB, 0, stream>>>(dinv, accs, w21, b21, y4, acc4, n);
    k_scat4<<<ge, TPB, 0, stream>>>(src, dst, E, y4, acc4);
    k_l2_to_l3<<<gn, TPB, 0, stream>>>(dinv, acc4, w22, b22, w23, ys, accs, n);
    k_scat1<<<ge, TPB, 0, stream>>>(src, dst, E, ys, accs);
    k_final<<<gn, TPB, 0, stream>>>(dinv, accs, b23, x2, out, sums, n);
    k_mean<<<1, 64, 0, stream>>>(sums, out, 1.f/(float)n);
  }
}

// Round 5
// 812.866 us; speedup vs baseline: 5.0907x; 1.2893x over previous
//
#include <hip/hip_runtime.h>
#include <hip/hip_bf16.h>

#define TPB 256
#define NSHADOW 8
#define NTEAM 8
#define TEAMS_PER 256   // blocks per team in k_fill_xcd

// ============================ build kernels ============================

__global__ void k_zero8(int* __restrict__ degS, int m){   // m = 8n
  int i = blockIdx.x*TPB + threadIdx.x;
  if(i < m) degS[i] = 0;
}

// 8-way shadowed degree histogram; shadow id = (e/TPB)&7 == blockIdx&7 here
__global__ void k_deg8(const int* __restrict__ dst, int E, int* __restrict__ degS, int n){
  int e = blockIdx.x*TPB + threadIdx.x;
  if(e < E) atomicAdd(&degS[(size_t)(blockIdx.x & (NSHADOW-1))*(size_t)n + dst[e]], 1);
}

// block sums of total degree
__global__ void k_bsum(const int* __restrict__ degS, int n, int* __restrict__ bsum){
  int i = blockIdx.x*TPB + threadIdx.x;
  int v = 0;
  if(i < n){
    #pragma unroll
    for(int s=0;s<NSHADOW;s++) v += degS[(size_t)s*(size_t)n + i];
  }
  #pragma unroll
  for(int off=32; off; off>>=1) v += __shfl_down(v, off, 64);
  __shared__ int ls[4];
  int lane = threadIdx.x & 63, w = threadIdx.x >> 6;
  if(lane == 0) ls[w] = v;
  __syncthreads();
  if(threadIdx.x == 0) bsum[blockIdx.x] = ls[0]+ls[1]+ls[2]+ls[3];
}

// single-block exclusive scan of block sums (nb <= 1024)
__global__ void k_bscan(int* __restrict__ bsum, int nb){
  __shared__ int s[1024];
  int t = threadIdx.x;
  int v = (t < nb) ? bsum[t] : 0;
  s[t] = v;
  __syncthreads();
  for(int off=1; off<1024; off<<=1){
    int add = (t >= off) ? s[t-off] : 0;
    __syncthreads();
    s[t] += add;
    __syncthreads();
  }
  if(t < nb) bsum[t] = s[t] - v;   // exclusive
}

// per-block scan of deg -> row_start; convert degS counts -> absolute sub-cursors IN PLACE;
// also deg, dinv, and gcn#1 input prep ysA = dinv * 10 * x
__global__ void k_rowstart2(int* __restrict__ degS /*in: counts, out: cursors*/,
                            const int* __restrict__ bsum, int n,
                            int* __restrict__ deg, int* __restrict__ row_start,
                            float* __restrict__ dinv,
                            const float* __restrict__ x, float* __restrict__ ysA){
  __shared__ int s[TPB];
  int i = blockIdx.x*TPB + threadIdx.x;
  int t = threadIdx.x;
  int c[NSHADOW];
  int v = 0;
  if(i < n){
    #pragma unroll
    for(int sh=0;sh<NSHADOW;sh++){ c[sh] = degS[(size_t)sh*(size_t)n + i]; v += c[sh]; }
  }
  s[t] = v;
  __syncthreads();
  for(int off=1; off<TPB; off<<=1){
    int add = (t >= off) ? s[t-off] : 0;
    __syncthreads();
    s[t] += add;
    __syncthreads();
  }
  if(i < n){
    int rs = bsum[blockIdx.x] + s[t] - v;
    deg[i]       = v;
    row_start[i] = rs;
    float dv = rsqrtf((float)(v + 1));   // +1 self loop
    dinv[i] = dv;
    ysA[i]  = dv * (10.f * x[i]);
    int base = rs;
    #pragma unroll
    for(int sh=0;sh<NSHADOW;sh++){ degS[(size_t)sh*(size_t)n + i] = base; base += c[sh]; }
  }
}

// XCD-affinity fill: team = blockIdx&7 owns node range [lo,hi); each team scans all edges.
// shadow id (e/TPB)&7 must match k_deg8's grouping (it does: chunk index == blockIdx there).
__global__ void k_fill_xcd(const int* __restrict__ src, const int* __restrict__ dst,
                           int E, int n, int* __restrict__ cursorS, int* __restrict__ csr){
  int team = blockIdx.x & (NTEAM-1);
  int tr   = blockIdx.x >> 3;          // team rank
  int lo = (int)(((long long)n * team) >> 3);
  int hi = (int)(((long long)n * (team+1)) >> 3);
  int nchunk = (E + TPB - 1) / TPB;
  for(int ci = tr; ci < nchunk; ci += TEAMS_PER){
    int e = ci*TPB + threadIdx.x;
    if(e < E){
      int d = dst[e];
      if(d >= lo && d < hi){
        int sh = ci & (NSHADOW-1);
        int pos = atomicAdd(&cursorS[(size_t)sh*(size_t)n + d], 1);
        csr[pos] = src[e];
      }
    }
  }
}

// ============================ fused gather layers ============================
// wave (64 lanes) per node; 4 nodes per 256-block

__global__ void k_gA(const int* __restrict__ csr, const int* __restrict__ row_start,
                     const int* __restrict__ deg, const float* __restrict__ dinv,
                     const float* __restrict__ ys, const float* __restrict__ W,
                     const float* __restrict__ B, float* __restrict__ y4, int n){
  int node = blockIdx.x*4 + (threadIdx.x >> 6);
  int lane = threadIdx.x & 63;
  if(node >= n) return;
  int rs = row_start[node], dg = deg[node];
  float s = 0.f;
  for(int j=lane; j<dg; j+=64) s += ys[csr[rs+j]];
  #pragma unroll
  for(int m=32; m; m>>=1) s += __shfl_xor(s, m, 64);
  if(lane == 0){
    float dv = dinv[node];
    float t  = dv * (ys[node] + s);
    float h0 = fmaxf(t*W[0]+B[0], 0.f);
    float h1 = fmaxf(t*W[1]+B[1], 0.f);
    float h2 = fmaxf(t*W[2]+B[2], 0.f);
    float h3 = fmaxf(t*W[3]+B[3], 0.f);
    *reinterpret_cast<float4*>(y4 + 4*(size_t)node) = make_float4(dv*h0, dv*h1, dv*h2, dv*h3);
  }
}

__global__ void k_gB(const int* __restrict__ csr, const int* __restrict__ row_start,
                     const int* __restrict__ deg, const float* __restrict__ dinv,
                     const float* __restrict__ y4, const float* __restrict__ W2,
                     const float* __restrict__ B2, const float* __restrict__ W3,
                     float* __restrict__ ys_out, int n){
  int node = blockIdx.x*4 + (threadIdx.x >> 6);
  int lane = threadIdx.x & 63;
  if(node >= n) return;
  int rs = row_start[node], dg = deg[node];
  float ax=0.f, ay=0.f, az=0.f, aw=0.f;
  for(int j=lane; j<dg; j+=64){
    float4 v = *reinterpret_cast<const float4*>(y4 + 4*(size_t)csr[rs+j]);
    ax += v.x; ay += v.y; az += v.z; aw += v.w;
  }
  #pragma unroll
  for(int m=32; m; m>>=1){
    ax += __shfl_xor(ax, m, 64);
    ay += __shfl_xor(ay, m, 64);
    az += __shfl_xor(az, m, 64);
    aw += __shfl_xor(aw, m, 64);
  }
  if(lane == 0){
    float dv = dinv[node];
    float4 sf = *reinterpret_cast<const float4*>(y4 + 4*(size_t)node);
    float z0 = dv*(ax+sf.x), z1 = dv*(ay+sf.y), z2 = dv*(az+sf.z), z3 = dv*(aw+sf.w);
    float s = 0.f;
    #pragma unroll
    for(int k=0;k<4;k++){
      float g = B2[k] + z0*W2[0*4+k] + z1*W2[1*4+k] + z2*W2[2*4+k] + z3*W2[3*4+k];
      g = fmaxf(g, 0.f);
      s += g * W3[k];
    }
    ys_out[node] = dv * s;
  }
}

__global__ void k_gC_mid(const int* __restrict__ csr, const int* __restrict__ row_start,
                         const int* __restrict__ deg, const float* __restrict__ dinv,
                         const float* __restrict__ ys, const float* __restrict__ B3,
                         float* __restrict__ x2, float* __restrict__ ys_out, int n){
  int node = blockIdx.x*4 + (threadIdx.x >> 6);
  int lane = threadIdx.x & 63;
  if(node >= n) return;
  int rs = row_start[node], dg = deg[node];
  float s = 0.f;
  for(int j=lane; j<dg; j+=64) s += ys[csr[rs+j]];
  #pragma unroll
  for(int m=32; m; m>>=1) s += __shfl_xor(s, m, 64);
  if(lane == 0){
    float dv = dinv[node];
    float u  = dv * (ys[node] + s) + B3[0];
    float v2 = sinf(10.f * u);
    x2[node] = v2;
    ys_out[node] = dv * v2;
  }
}

// gcn#2 layer3 finish: x3; node embeddings + per-block partial sums (no same-address atomics)
__global__ void k_gC_fin(const int* __restrict__ csr, const int* __restrict__ row_start,
                         const int* __restrict__ deg, const float* __restrict__ dinv,
                         const float* __restrict__ ys, const float* __restrict__ B3,
                         const float* __restrict__ x2, float* __restrict__ out,
                         float* __restrict__ pbuf, int n){
  int node = blockIdx.x*4 + (threadIdx.x >> 6);
  int lane = threadIdx.x & 63;
  int w = threadIdx.x >> 6;
  bool act = node < n;
  float v2 = 0.f, x3 = 0.f;
  if(act){
    int rs = row_start[node], dg = deg[node];
    float s = 0.f;
    for(int j=lane; j<dg; j+=64) s += ys[csr[rs+j]];
    #pragma unroll
    for(int m=32; m; m>>=1) s += __shfl_xor(s, m, 64);
    x3 = dinv[node] * (ys[node] + s) + B3[0];
    v2 = x2[node];
  }
  __shared__ float p2[4], p3[4];
  if(lane == 0){
    p2[w] = act ? v2 : 0.f;
    p3[w] = act ? x3 : 0.f;
    if(act)
      *reinterpret_cast<float2*>(out + 2 + 2*(size_t)node) = make_float2(v2, x3);
  }
  __syncthreads();
  if(threadIdx.x == 0){
    pbuf[2*(size_t)blockIdx.x]   = p2[0]+p2[1]+p2[2]+p2[3];
    pbuf[2*(size_t)blockIdx.x+1] = p3[0]+p3[1]+p3[2]+p3[3];
  }
}

__global__ void k_reduce_mean(const float* __restrict__ pbuf, int nb,
                              float* __restrict__ out, float invn){
  float s2 = 0.f, s3 = 0.f;
  for(int i = threadIdx.x; i < nb; i += 1024){
    s2 += pbuf[2*i];
    s3 += pbuf[2*i+1];
  }
  #pragma unroll
  for(int m=32; m; m>>=1){ s2 += __shfl_xor(s2, m, 64); s3 += __shfl_xor(s3, m, 64); }
  __shared__ float a2[16], a3[16];
  int w = threadIdx.x >> 6, lane = threadIdx.x & 63;
  if(lane == 0){ a2[w] = s2; a3[w] = s3; }
  __syncthreads();
  if(threadIdx.x == 0){
    float t2 = 0.f, t3 = 0.f;
    #pragma unroll
    for(int k=0;k<16;k++){ t2 += a2[k]; t3 += a3[k]; }
    out[0] = t2 * invn;
    out[1] = t3 * invn;
  }
}

// ============================ fallback (atomic scatter, round-2 path) ============================

__global__ void k_init(int* __restrict__ deg, float* __restrict__ sums, int n){
  int i = blockIdx.x*TPB + threadIdx.x;
  if(i < n) deg[i] = 0;
  if(i < 2) sums[i] = 0.f;
}

__global__ void k_deg(const int* __restrict__ dst, int E, int* __restrict__ deg){
  int e = blockIdx.x*TPB + threadIdx.x;
  if(e < E) atomicAdd(&deg[dst[e]], 1);
}

__global__ void k_dinv(const int* __restrict__ deg, float* __restrict__ dinv, int n){
  int i = blockIdx.x*TPB + threadIdx.x;
  if(i < n) dinv[i] = rsqrtf((float)(deg[i] + 1));
}

__global__ void k_prep_first2(const float* __restrict__ x, const float* __restrict__ dinv,
                              float* __restrict__ ys, float* __restrict__ accs, int n){
  int i = blockIdx.x*TPB + threadIdx.x;
  if(i < n){ float u = dinv[i]*(10.f*x[i]); ys[i]=u; accs[i]=u; }
}

__global__ void k_scat1(const int* __restrict__ src, const int* __restrict__ dst, int E,
                        const float* __restrict__ ys, float* __restrict__ accs){
  int e = blockIdx.x*TPB + threadIdx.x;
  if(e < E) atomicAdd(&accs[dst[e]], ys[src[e]]);
}

__global__ void k_l1_to_l2(const float* __restrict__ dinv, const float* __restrict__ accs,
                           const float* __restrict__ W1, const float* __restrict__ B1,
                           float* __restrict__ y4, float* __restrict__ acc4, int n){
  int i = blockIdx.x*TPB + threadIdx.x;
  if(i < n){
    float dv = dinv[i];
    float t  = dv * accs[i];
    float h0 = fmaxf(t*W1[0]+B1[0],0.f);
    float h1 = fmaxf(t*W1[1]+B1[1],0.f);
    float h2 = fmaxf(t*W1[2]+B1[2],0.f);
    float h3 = fmaxf(t*W1[3]+B1[3],0.f);
    float4 u = make_float4(dv*h0,dv*h1,dv*h2,dv*h3);
    *reinterpret_cast<float4*>(y4  + 4*(size_t)i) = u;
    *reinterpret_cast<float4*>(acc4 + 4*(size_t)i) = u;
  }
}

__global__ void k_scat4(const int* __restrict__ src, const int* __restrict__ dst, int E,
                        const float* __restrict__ y4, float* __restrict__ acc4){
  int e = blockIdx.x*TPB + threadIdx.x;
  if(e < E){
    int s = src[e], d = dst[e];
    float4 v = *reinterpret_cast<const float4*>(y4 + 4*(size_t)s);
    float* base = acc4 + 4*(size_t)d;
    atomicAdd(base+0, v.x); atomicAdd(base+1, v.y);
    atomicAdd(base+2, v.z); atomicAdd(base+3, v.w);
  }
}

__global__ void k_l2_to_l3(const float* __restrict__ dinv, const float* __restrict__ acc4,
                           const float* __restrict__ W2, const float* __restrict__ B2,
                           const float* __restrict__ W3,
                           float* __restrict__ ys, float* __restrict__ accs, int n){
  int i = blockIdx.x*TPB + threadIdx.x;
  if(i < n){
    float dv = dinv[i];
    float4 a = *reinterpret_cast<const float4*>(acc4 + 4*(size_t)i);
    float z0=dv*a.x, z1=dv*a.y, z2=dv*a.z, z3=dv*a.w;
    float s = 0.f;
    #pragma unroll
    for(int k=0;k<4;k++){
      float g = B2[k] + z0*W2[0*4+k] + z1*W2[1*4+k] + z2*W2[2*4+k] + z3*W2[3*4+k];
      g = fmaxf(g,0.f);
      s += g * W3[k];
    }
    float u = dv*s; ys[i]=u; accs[i]=u;
  }
}

__global__ void k_mid(const float* __restrict__ dinv, const float* __restrict__ B3,
                      float* __restrict__ x2, float* __restrict__ ys,
                      float* __restrict__ accs, int n){
  int i = blockIdx.x*TPB + threadIdx.x;
  if(i < n){
    float v = dinv[i]*accs[i] + B3[0];
    float s2 = sinf(10.f*v);
    x2[i]=s2;
    float u = dinv[i]*s2;
    ys[i]=u; accs[i]=u;
  }
}

__global__ void k_final(const float* __restrict__ dinv, const float* __restrict__ accs,
                        const float* __restrict__ B3, const float* __restrict__ x2,
                        float* __restrict__ out, float* __restrict__ sums, int n){
  int i = blockIdx.x*TPB + threadIdx.x;
  float sx2=0.f, sx3=0.f;
  if(i < n){
    float x3 = dinv[i]*accs[i] + B3[0];
    float v2 = x2[i];
    *reinterpret_cast<float2*>(out + 2 + 2*(size_t)i) = make_float2(v2, x3);
    sx2=v2; sx3=x3;
  }
  #pragma unroll
  for(int off=32; off; off>>=1){
    sx2 += __shfl_down(sx2, off, 64);
    sx3 += __shfl_down(sx3, off, 64);
  }
  __shared__ float l2s[4], l3s[4];
  int lane = threadIdx.x & 63, w = threadIdx.x >> 6;
  if(lane==0){ l2s[w]=sx2; l3s[w]=sx3; }
  __syncthreads();
  if(threadIdx.x==0){
    atomicAdd(&sums[0], l2s[0]+l2s[1]+l2s[2]+l2s[3]);
    atomicAdd(&sums[1], l3s[0]+l3s[1]+l3s[2]+l3s[3]);
  }
}

__global__ void k_mean(const float* __restrict__ sums, float* __restrict__ out, float invn){
  if(threadIdx.x == 0){
    out[0] = sums[0] * invn;
    out[1] = sums[1] * invn;
  }
}

// ============================ launch ============================

extern "C" void kernel_launch(void* const* d_in, const int* in_sizes, int n_in,
                              void* d_out, int out_size, void* d_ws, size_t ws_size,
                              hipStream_t stream) {
  const float* x   = (const float*)d_in[0];
  const int*   ei  = (const int*)  d_in[1];
  const float* w11 = (const float*)d_in[2];
  const float* b11 = (const float*)d_in[3];
  const float* w12 = (const float*)d_in[4];
  const float* b12 = (const float*)d_in[5];
  const float* w13 = (const float*)d_in[6];
  const float* b13 = (const float*)d_in[7];
  const float* w21 = (const float*)d_in[8];
  const float* b21 = (const float*)d_in[9];
  const float* w22 = (const float*)d_in[10];
  const float* b22 = (const float*)d_in[11];
  const float* w23 = (const float*)d_in[12];
  const float* b23 = (const float*)d_in[13];
  float* out = (float*)d_out;

  const int n = in_sizes[0];
  const int E = in_sizes[1] / 2;
  const int* src = ei;
  const int* dst = ei + E;

  const int gn  = (n + TPB - 1)/TPB;
  const int ge  = (E + TPB - 1)/TPB;
  const int gn4 = (n + 3)/4;

  float* ws = (float*)d_ws;

  const size_t need = (size_t)(18*(size_t)n + 1024 + (size_t)E) * 4;
  if(ws_size >= need && gn <= 1024 && (size_t)E >= (size_t)NSHADOW*(size_t)n){
    // ---------------- CSR gather path ----------------
    float* y4        = ws;                           // 4n; aliased as pbuf in finale
    float* dinv      = ws + 4*(size_t)n;             // n
    float* ysA       = ws + 5*(size_t)n;             // n
    float* ysB       = ws + 6*(size_t)n;             // n
    float* x2        = ws + 7*(size_t)n;             // n
    int*   deg       = (int*)(ws + 8*(size_t)n);     // n
    int*   row_start = (int*)(ws + 9*(size_t)n);     // n
    int*   bsum      = (int*)(ws + 10*(size_t)n);    // 1024
    int*   degS      = (int*)(ws + 10*(size_t)n + 1024); // 8n (counts -> cursors in place)
    int*   csr       = degS + 8*(size_t)n;           // E
    float* pbuf      = y4;                           // alias, y4 dead before k_gC_fin

    const int m8 = NSHADOW*n;
    k_zero8    <<<(m8+TPB-1)/TPB, TPB, 0, stream>>>(degS, m8);
    k_deg8     <<<ge, TPB, 0, stream>>>(dst, E, degS, n);
    k_bsum     <<<gn, TPB, 0, stream>>>(degS, n, bsum);
    k_bscan    <<<1, 1024, 0, stream>>>(bsum, gn);
    k_rowstart2<<<gn, TPB, 0, stream>>>(degS, bsum, n, deg, row_start, dinv, x, ysA);
    k_fill_xcd <<<NTEAM*TEAMS_PER, TPB, 0, stream>>>(src, dst, E, n, degS, csr);

    // gcn #1
    k_gA    <<<gn4, TPB, 0, stream>>>(csr, row_start, deg, dinv, ysA, w11, b11, y4, n);
    k_gB    <<<gn4, TPB, 0, stream>>>(csr, row_start, deg, dinv, y4, w12, b12, w13, ysB, n);
    k_gC_mid<<<gn4, TPB, 0, stream>>>(csr, row_start, deg, dinv, ysB, b13, x2, ysA, n);
    // gcn #2
    k_gA    <<<gn4, TPB, 0, stream>>>(csr, row_start, deg, dinv, ysA, w21, b21, y4, n);
    k_gB    <<<gn4, TPB, 0, stream>>>(csr, row_start, deg, dinv, y4, w22, b22, w23, ysB, n);
    k_gC_fin<<<gn4, TPB, 0, stream>>>(csr, row_start, deg, dinv, ysB, b23, x2, out, pbuf, n);
    k_reduce_mean<<<1, 1024, 0, stream>>>(pbuf, gn4, out, 1.f/(float)n);
  } else {
    // ---------------- fallback: atomic scatter path ----------------
    float* dinv = ws;                     // n
    int*   deg  = (int*)(ws + n);         // n
    float* ys   = ws + 2*(size_t)n;       // n
    float* accs = ws + 3*(size_t)n;       // n
    float* y4   = ws + 4*(size_t)n;       // 4n
    float* acc4 = ws + 8*(size_t)n;       // 4n
    float* x2   = ws + 12*(size_t)n;      // n
    float* sums = ws + 13*(size_t)n;      // 2

    k_init<<<gn, TPB, 0, stream>>>(deg, sums, n);
    k_deg <<<ge, TPB, 0, stream>>>(dst, E, deg);
    k_dinv<<<gn, TPB, 0, stream>>>(deg, dinv, n);

    k_prep_first2<<<gn, TPB, 0, stream>>>(x, dinv, ys, accs, n);
    k_scat1<<<ge, TPB, 0, stream>>>(src, dst, E, ys, accs);
    k_l1_to_l2<<<gn, TPB, 0, stream>>>(dinv, accs, w11, b11, y4, acc4, n);
    k_scat4<<<ge, TPB, 0, stream>>>(src, dst, E, y4, acc4);
    k_l2_to_l3<<<gn, TPB, 0, stream>>>(dinv, acc4, w12, b12, w13, ys, accs, n);
    k_scat1<<<ge, TPB, 0, stream>>>(src, dst, E, ys, accs);
    k_mid<<<gn, TPB, 0, stream>>>(dinv, b13, x2, ys, accs, n);

    k_scat1<<<ge, TPB, 0, stream>>>(src, dst, E, ys, accs);
    k_l1_to_l2<<<gn, TPB, 0, stream>>>(dinv, accs, w21, b21, y4, acc4, n);
    k_scat4<<<ge, TPB, 0, stream>>>(src, dst, E, y4, acc4);
    k_l2_to_l3<<<gn, TPB, 0, stream>>>(dinv, acc4, w22, b22, w23, ys, accs, n);
    k_scat1<<<ge, TPB, 0, stream>>>(src, dst, E, ys, accs);
    k_final<<<gn, TPB, 0, stream>>>(dinv, accs, b23, x2, out, sums, n);
    k_mean<<<1, 64, 0, stream>>>(sums, out, 1.f/(float)n);
  }
}

// Round 6
// 500.587 us; speedup vs baseline: 8.2665x; 1.6238x over previous
//
#include <hip/hip_runtime.h>
#include <hip/hip_bf16.h>

#define TPB 256
#define NB 256          // partition buckets
#define MAXW 512        // max nodes per bucket supported
#define P1K 32          // edges per thread per phase-1 chunk
#define NSHADOW 8       // fallback path
#define NTEAM 8
#define TEAMS_PER 256

// ============================ bucketed CSR build (atomic-light) ============================

// per-block 256-bin histogram of dst buckets
__global__ void k_bcount(const int* __restrict__ dst, int E, int n, int* __restrict__ bhist){
  __shared__ int lh[NB];
  lh[threadIdx.x] = 0;
  __syncthreads();
  int stride = gridDim.x * TPB;
  for(int e = blockIdx.x*TPB + threadIdx.x; e < E; e += stride){
    int b = (int)(((long long)dst[e] * NB) / n);
    atomicAdd(&lh[b], 1);
  }
  __syncthreads();
  bhist[blockIdx.x*NB + threadIdx.x] = lh[threadIdx.x];
}

// single block: column-sum bhist -> sizes; exclusive scan -> bucket_base, gcur
__global__ void k_bucketscan(const int* __restrict__ bhist, int nblk, int E,
                             int* __restrict__ bucket_base, int* __restrict__ gcur){
  __shared__ int sa[NB], sb[NB];
  int t = threadIdx.x;
  int s = 0;
  for(int g = 0; g < nblk; ++g) s += bhist[g*NB + t];
  sa[t] = s;
  __syncthreads();
  int *pa = sa, *pb = sb;
  for(int off = 1; off < NB; off <<= 1){
    pb[t] = pa[t] + (t >= off ? pa[t-off] : 0);
    __syncthreads();
    int* tmp = pa; pa = pb; pb = tmp;
  }
  int excl = pa[t] - s;
  bucket_base[t] = excl;
  gcur[t]        = excl;
  if(t == 0) bucket_base[NB] = E;
}

// partition edges into dst-ordered buckets as packed (src | dstLocal<<sbits)
__global__ void k_phase1(const int* __restrict__ src, const int* __restrict__ dst,
                         int E, int n, int* __restrict__ gcur,
                         unsigned* __restrict__ temp, int sbits){
  __shared__ int lhist[NB], lbase[NB], lrank[NB];
  const int CH = TPB * P1K;
  int nchunk = (E + CH - 1) / CH;
  for(int c = blockIdx.x; c < nchunk; c += gridDim.x){
    int cb = c * CH;
    lhist[threadIdx.x] = 0;
    __syncthreads();
    #pragma unroll 4
    for(int i = 0; i < P1K; i++){
      int e = cb + i*TPB + threadIdx.x;
      if(e < E){
        int b = (int)(((long long)dst[e] * NB) / n);
        atomicAdd(&lhist[b], 1);
      }
    }
    __syncthreads();
    int h = lhist[threadIdx.x];
    if(h > 0) lbase[threadIdx.x] = atomicAdd(&gcur[threadIdx.x], h);
    lrank[threadIdx.x] = 0;
    __syncthreads();
    #pragma unroll 4
    for(int i = 0; i < P1K; i++){
      int e = cb + i*TPB + threadIdx.x;
      if(e < E){
        int d = dst[e];
        int b = (int)(((long long)d * NB) / n);
        int lo = (int)(((long long)n * b + NB - 1) / NB);
        int r = atomicAdd(&lrank[b], 1);
        temp[lbase[b] + r] = (unsigned)src[e] | ((unsigned)(d - lo) << sbits);
      }
    }
    __syncthreads();
  }
}

// per bucket (1 block): LDS degree histogram + LDS scan -> deg,row_start,dinv,ysA. No atomics.
__global__ void k_ldeg_scan(const unsigned* __restrict__ temp, const int* __restrict__ bucket_base,
                            int n, int sbits,
                            int* __restrict__ deg, int* __restrict__ row_start,
                            float* __restrict__ dinv,
                            const float* __restrict__ x, float* __restrict__ ysA){
  __shared__ int hist[MAXW], sa[MAXW], sb[MAXW];
  int b = blockIdx.x;
  int lo = (int)(((long long)n * b + NB - 1) / NB);
  int hi = (int)(((long long)n * (b+1) + NB - 1) / NB);
  if(hi > n) hi = n;
  int width = hi - lo;
  for(int l = threadIdx.x; l < MAXW; l += TPB) hist[l] = 0;
  __syncthreads();
  int e0 = bucket_base[b], e1 = bucket_base[b+1];
  for(int idx = e0 + threadIdx.x; idx < e1; idx += TPB)
    atomicAdd(&hist[temp[idx] >> sbits], 1);
  __syncthreads();
  int *pa = sa, *pb = sb;
  for(int l = threadIdx.x; l < MAXW; l += TPB) pa[l] = hist[l];
  __syncthreads();
  for(int off = 1; off < MAXW; off <<= 1){
    for(int l = threadIdx.x; l < MAXW; l += TPB)
      pb[l] = pa[l] + (l >= off ? pa[l-off] : 0);
    __syncthreads();
    int* tmp = pa; pa = pb; pb = tmp;
  }
  for(int l = threadIdx.x; l < width; l += TPB){
    int cnt  = hist[l];
    int node = lo + l;
    deg[node]       = cnt;
    row_start[node] = e0 + pa[l] - cnt;
    float dv = rsqrtf((float)(cnt + 1));   // +1 self loop
    dinv[node] = dv;
    ysA[node]  = dv * (10.f * x[node]);
  }
}

// per bucket (1 block): scatter packed entries into exact csr slots via LDS cursors
__global__ void k_phase2(const unsigned* __restrict__ temp, const int* __restrict__ bucket_base,
                         const int* __restrict__ row_start, int n, int sbits, unsigned smask,
                         int* __restrict__ csr){
  __shared__ int cur[MAXW];
  int b = blockIdx.x;
  int lo = (int)(((long long)n * b + NB - 1) / NB);
  int hi = (int)(((long long)n * (b+1) + NB - 1) / NB);
  if(hi > n) hi = n;
  int width = hi - lo;
  for(int l = threadIdx.x; l < width; l += TPB) cur[l] = row_start[lo + l];
  __syncthreads();
  int e0 = bucket_base[b], e1 = bucket_base[b+1];
  for(int idx = e0 + threadIdx.x; idx < e1; idx += TPB){
    unsigned u = temp[idx];
    int pos = atomicAdd(&cur[u >> sbits], 1);
    csr[pos] = (int)(u & smask);
  }
}

// ============================ fused gather layers ============================
// wave (64 lanes) per node; 4 nodes per 256-block

__global__ void k_gA(const int* __restrict__ csr, const int* __restrict__ row_start,
                     const int* __restrict__ deg, const float* __restrict__ dinv,
                     const float* __restrict__ ys, const float* __restrict__ W,
                     const float* __restrict__ B, float* __restrict__ y4, int n){
  int node = blockIdx.x*4 + (threadIdx.x >> 6);
  int lane = threadIdx.x & 63;
  if(node >= n) return;
  int rs = row_start[node], dg = deg[node];
  float s = 0.f;
  for(int j=lane; j<dg; j+=64) s += ys[csr[rs+j]];
  #pragma unroll
  for(int m=32; m; m>>=1) s += __shfl_xor(s, m, 64);
  if(lane == 0){
    float dv = dinv[node];
    float t  = dv * (ys[node] + s);
    float h0 = fmaxf(t*W[0]+B[0], 0.f);
    float h1 = fmaxf(t*W[1]+B[1], 0.f);
    float h2 = fmaxf(t*W[2]+B[2], 0.f);
    float h3 = fmaxf(t*W[3]+B[3], 0.f);
    *reinterpret_cast<float4*>(y4 + 4*(size_t)node) = make_float4(dv*h0, dv*h1, dv*h2, dv*h3);
  }
}

__global__ void k_gB(const int* __restrict__ csr, const int* __restrict__ row_start,
                     const int* __restrict__ deg, const float* __restrict__ dinv,
                     const float* __restrict__ y4, const float* __restrict__ W2,
                     const float* __restrict__ B2, const float* __restrict__ W3,
                     float* __restrict__ ys_out, int n){
  int node = blockIdx.x*4 + (threadIdx.x >> 6);
  int lane = threadIdx.x & 63;
  if(node >= n) return;
  int rs = row_start[node], dg = deg[node];
  float ax=0.f, ay=0.f, az=0.f, aw=0.f;
  for(int j=lane; j<dg; j+=64){
    float4 v = *reinterpret_cast<const float4*>(y4 + 4*(size_t)csr[rs+j]);
    ax += v.x; ay += v.y; az += v.z; aw += v.w;
  }
  #pragma unroll
  for(int m=32; m; m>>=1){
    ax += __shfl_xor(ax, m, 64);
    ay += __shfl_xor(ay, m, 64);
    az += __shfl_xor(az, m, 64);
    aw += __shfl_xor(aw, m, 64);
  }
  if(lane == 0){
    float dv = dinv[node];
    float4 sf = *reinterpret_cast<const float4*>(y4 + 4*(size_t)node);
    float z0 = dv*(ax+sf.x), z1 = dv*(ay+sf.y), z2 = dv*(az+sf.z), z3 = dv*(aw+sf.w);
    float s = 0.f;
    #pragma unroll
    for(int k=0;k<4;k++){
      float g = B2[k] + z0*W2[0*4+k] + z1*W2[1*4+k] + z2*W2[2*4+k] + z3*W2[3*4+k];
      g = fmaxf(g, 0.f);
      s += g * W3[k];
    }
    ys_out[node] = dv * s;
  }
}

__global__ void k_gC_mid(const int* __restrict__ csr, const int* __restrict__ row_start,
                         const int* __restrict__ deg, const float* __restrict__ dinv,
                         const float* __restrict__ ys, const float* __restrict__ B3,
                         float* __restrict__ x2, float* __restrict__ ys_out, int n){
  int node = blockIdx.x*4 + (threadIdx.x >> 6);
  int lane = threadIdx.x & 63;
  if(node >= n) return;
  int rs = row_start[node], dg = deg[node];
  float s = 0.f;
  for(int j=lane; j<dg; j+=64) s += ys[csr[rs+j]];
  #pragma unroll
  for(int m=32; m; m>>=1) s += __shfl_xor(s, m, 64);
  if(lane == 0){
    float dv = dinv[node];
    float u  = dv * (ys[node] + s) + B3[0];
    float v2 = sinf(10.f * u);
    x2[node] = v2;
    ys_out[node] = dv * v2;
  }
}

__global__ void k_gC_fin(const int* __restrict__ csr, const int* __restrict__ row_start,
                         const int* __restrict__ deg, const float* __restrict__ dinv,
                         const float* __restrict__ ys, const float* __restrict__ B3,
                         const float* __restrict__ x2, float* __restrict__ out,
                         float* __restrict__ pbuf, int n){
  int node = blockIdx.x*4 + (threadIdx.x >> 6);
  int lane = threadIdx.x & 63;
  int w = threadIdx.x >> 6;
  bool act = node < n;
  float v2 = 0.f, x3 = 0.f;
  if(act){
    int rs = row_start[node], dg = deg[node];
    float s = 0.f;
    for(int j=lane; j<dg; j+=64) s += ys[csr[rs+j]];
    #pragma unroll
    for(int m=32; m; m>>=1) s += __shfl_xor(s, m, 64);
    x3 = dinv[node] * (ys[node] + s) + B3[0];
    v2 = x2[node];
  }
  __shared__ float p2[4], p3[4];
  if(lane == 0){
    p2[w] = act ? v2 : 0.f;
    p3[w] = act ? x3 : 0.f;
    if(act)
      *reinterpret_cast<float2*>(out + 2 + 2*(size_t)node) = make_float2(v2, x3);
  }
  __syncthreads();
  if(threadIdx.x == 0){
    pbuf[2*(size_t)blockIdx.x]   = p2[0]+p2[1]+p2[2]+p2[3];
    pbuf[2*(size_t)blockIdx.x+1] = p3[0]+p3[1]+p3[2]+p3[3];
  }
}

__global__ void k_reduce_mean(const float* __restrict__ pbuf, int nb,
                              float* __restrict__ out, float invn){
  float s2 = 0.f, s3 = 0.f;
  for(int i = threadIdx.x; i < nb; i += 1024){
    s2 += pbuf[2*i];
    s3 += pbuf[2*i+1];
  }
  #pragma unroll
  for(int m=32; m; m>>=1){ s2 += __shfl_xor(s2, m, 64); s3 += __shfl_xor(s3, m, 64); }
  __shared__ float a2[16], a3[16];
  int w = threadIdx.x >> 6, lane = threadIdx.x & 63;
  if(lane == 0){ a2[w] = s2; a3[w] = s3; }
  __syncthreads();
  if(threadIdx.x == 0){
    float t2 = 0.f, t3 = 0.f;
    #pragma unroll
    for(int k=0;k<16;k++){ t2 += a2[k]; t3 += a3[k]; }
    out[0] = t2 * invn;
    out[1] = t3 * invn;
  }
}

// ============================ fallback build (round-5: shadowed deg + XCD fill) ============================

__global__ void k_zero8(int* __restrict__ degS, int m){
  int i = blockIdx.x*TPB + threadIdx.x;
  if(i < m) degS[i] = 0;
}

__global__ void k_deg8(const int* __restrict__ dst, int E, int* __restrict__ degS, int n){
  int e = blockIdx.x*TPB + threadIdx.x;
  if(e < E) atomicAdd(&degS[(size_t)(blockIdx.x & (NSHADOW-1))*(size_t)n + dst[e]], 1);
}

__global__ void k_bsum(const int* __restrict__ degS, int n, int* __restrict__ bsum){
  int i = blockIdx.x*TPB + threadIdx.x;
  int v = 0;
  if(i < n){
    #pragma unroll
    for(int s=0;s<NSHADOW;s++) v += degS[(size_t)s*(size_t)n + i];
  }
  #pragma unroll
  for(int off=32; off; off>>=1) v += __shfl_down(v, off, 64);
  __shared__ int ls[4];
  int lane = threadIdx.x & 63, w = threadIdx.x >> 6;
  if(lane == 0) ls[w] = v;
  __syncthreads();
  if(threadIdx.x == 0) bsum[blockIdx.x] = ls[0]+ls[1]+ls[2]+ls[3];
}

__global__ void k_bscan(int* __restrict__ bsum, int nb){
  __shared__ int s[1024];
  int t = threadIdx.x;
  int v = (t < nb) ? bsum[t] : 0;
  s[t] = v;
  __syncthreads();
  for(int off=1; off<1024; off<<=1){
    int add = (t >= off) ? s[t-off] : 0;
    __syncthreads();
    s[t] += add;
    __syncthreads();
  }
  if(t < nb) bsum[t] = s[t] - v;
}

__global__ void k_rowstart2(int* __restrict__ degS, const int* __restrict__ bsum, int n,
                            int* __restrict__ deg, int* __restrict__ row_start,
                            float* __restrict__ dinv,
                            const float* __restrict__ x, float* __restrict__ ysA){
  __shared__ int s[TPB];
  int i = blockIdx.x*TPB + threadIdx.x;
  int t = threadIdx.x;
  int c[NSHADOW];
  int v = 0;
  if(i < n){
    #pragma unroll
    for(int sh=0;sh<NSHADOW;sh++){ c[sh] = degS[(size_t)sh*(size_t)n + i]; v += c[sh]; }
  }
  s[t] = v;
  __syncthreads();
  for(int off=1; off<TPB; off<<=1){
    int add = (t >= off) ? s[t-off] : 0;
    __syncthreads();
    s[t] += add;
    __syncthreads();
  }
  if(i < n){
    int rs = bsum[blockIdx.x] + s[t] - v;
    deg[i]       = v;
    row_start[i] = rs;
    float dv = rsqrtf((float)(v + 1));
    dinv[i] = dv;
    ysA[i]  = dv * (10.f * x[i]);
    int base = rs;
    #pragma unroll
    for(int sh=0;sh<NSHADOW;sh++){ degS[(size_t)sh*(size_t)n + i] = base; base += c[sh]; }
  }
}

__global__ void k_fill_xcd(const int* __restrict__ src, const int* __restrict__ dst,
                           int E, int n, int* __restrict__ cursorS, int* __restrict__ csr){
  int team = blockIdx.x & (NTEAM-1);
  int tr   = blockIdx.x >> 3;
  int lo = (int)(((long long)n * team) >> 3);
  int hi = (int)(((long long)n * (team+1)) >> 3);
  int nchunk = (E + TPB - 1) / TPB;
  for(int ci = tr; ci < nchunk; ci += TEAMS_PER){
    int e = ci*TPB + threadIdx.x;
    if(e < E){
      int d = dst[e];
      if(d >= lo && d < hi){
        int sh = ci & (NSHADOW-1);
        int pos = atomicAdd(&cursorS[(size_t)sh*(size_t)n + d], 1);
        csr[pos] = src[e];
      }
    }
  }
}

// ============================ launch ============================

extern "C" void kernel_launch(void* const* d_in, const int* in_sizes, int n_in,
                              void* d_out, int out_size, void* d_ws, size_t ws_size,
                              hipStream_t stream) {
  const float* x   = (const float*)d_in[0];
  const int*   ei  = (const int*)  d_in[1];
  const float* w11 = (const float*)d_in[2];
  const float* b11 = (const float*)d_in[3];
  const float* w12 = (const float*)d_in[4];
  const float* b12 = (const float*)d_in[5];
  const float* w13 = (const float*)d_in[6];
  const float* b13 = (const float*)d_in[7];
  const float* w21 = (const float*)d_in[8];
  const float* b21 = (const float*)d_in[9];
  const float* w22 = (const float*)d_in[10];
  const float* b22 = (const float*)d_in[11];
  const float* w23 = (const float*)d_in[12];
  const float* b23 = (const float*)d_in[13];
  float* out = (float*)d_out;

  const int n = in_sizes[0];
  const int E = in_sizes[1] / 2;
  const int* src = ei;
  const int* dst = ei + E;

  const int gn  = (n + TPB - 1)/TPB;
  const int gn4 = (n + 3)/4;
  const int ge  = (E + TPB - 1)/TPB;

  float* ws = (float*)d_ws;

  // packing parameters for bucket path
  int sbits = 1; while((1 << sbits) < n && sbits < 31) sbits++;          // bits for src
  int maxw  = (n + NB - 1) / NB;
  int dbits = 1; while((1 << dbits) < maxw && dbits < 31) dbits++;       // bits for dstLocal
  unsigned smask = (sbits >= 31) ? 0x7FFFFFFFu : ((1u << sbits) - 1u);

  const size_t need_bucket = ((size_t)10*n + 1024 + (size_t)512*NB + 2*(size_t)E + 64) * 4;
  const size_t need_r5     = ((size_t)18*n + 1024 + (size_t)E) * 4;

  if(ws_size >= need_bucket && n >= NB && maxw <= MAXW && (sbits + dbits) <= 32){
    // ---------------- bucketed-build CSR path ----------------
    float*    y4          = ws;                               // 4n (pbuf alias later)
    float*    dinv        = ws + 4*(size_t)n;                 // n
    float*    ysA         = ws + 5*(size_t)n;                 // n
    float*    ysB         = ws + 6*(size_t)n;                 // n
    float*    x2          = ws + 7*(size_t)n;                 // n
    int*      deg         = (int*)(ws + 8*(size_t)n);         // n
    int*      row_start   = (int*)(ws + 9*(size_t)n);         // n
    int*      bucket_base = (int*)(ws + 10*(size_t)n);        // NB+1 (pad 512)
    int*      gcur        = bucket_base + 512;                // NB (pad 512)
    int*      bhist       = gcur + 512;                       // 512*NB
    unsigned* temp        = (unsigned*)(bhist + 512*NB);      // E
    int*      csr         = (int*)(temp + (size_t)E);         // E
    float*    pbuf        = y4;

    k_bcount    <<<512, TPB, 0, stream>>>(dst, E, n, bhist);
    k_bucketscan<<<1,   NB,  0, stream>>>(bhist, 512, E, bucket_base, gcur);
    k_phase1    <<<512, TPB, 0, stream>>>(src, dst, E, n, gcur, temp, sbits);
    k_ldeg_scan <<<NB,  TPB, 0, stream>>>(temp, bucket_base, n, sbits, deg, row_start, dinv, x, ysA);
    k_phase2    <<<NB,  TPB, 0, stream>>>(temp, bucket_base, row_start, n, sbits, smask, csr);

    // gcn #1
    k_gA    <<<gn4, TPB, 0, stream>>>(csr, row_start, deg, dinv, ysA, w11, b11, y4, n);
    k_gB    <<<gn4, TPB, 0, stream>>>(csr, row_start, deg, dinv, y4, w12, b12, w13, ysB, n);
    k_gC_mid<<<gn4, TPB, 0, stream>>>(csr, row_start, deg, dinv, ysB, b13, x2, ysA, n);
    // gcn #2
    k_gA    <<<gn4, TPB, 0, stream>>>(csr, row_start, deg, dinv, ysA, w21, b21, y4, n);
    k_gB    <<<gn4, TPB, 0, stream>>>(csr, row_start, deg, dinv, y4, w22, b22, w23, ysB, n);
    k_gC_fin<<<gn4, TPB, 0, stream>>>(csr, row_start, deg, dinv, ysB, b23, x2, out, pbuf, n);
    k_reduce_mean<<<1, 1024, 0, stream>>>(pbuf, gn4, out, 1.f/(float)n);
  } else if(ws_size >= need_r5 && gn <= 1024 && (size_t)E >= (size_t)NSHADOW*(size_t)n){
    // ---------------- round-5 CSR path (fallback) ----------------
    float* y4        = ws;
    float* dinv      = ws + 4*(size_t)n;
    float* ysA       = ws + 5*(size_t)n;
    float* ysB       = ws + 6*(size_t)n;
    float* x2        = ws + 7*(size_t)n;
    int*   deg       = (int*)(ws + 8*(size_t)n);
    int*   row_start = (int*)(ws + 9*(size_t)n);
    int*   bsum      = (int*)(ws + 10*(size_t)n);
    int*   degS      = (int*)(ws + 10*(size_t)n + 1024);
    int*   csr       = degS + 8*(size_t)n;
    float* pbuf      = y4;

    const int m8 = NSHADOW*n;
    k_zero8    <<<(m8+TPB-1)/TPB, TPB, 0, stream>>>(degS, m8);
    k_deg8     <<<ge, TPB, 0, stream>>>(dst, E, degS, n);
    k_bsum     <<<gn, TPB, 0, stream>>>(degS, n, bsum);
    k_bscan    <<<1, 1024, 0, stream>>>(bsum, gn);
    k_rowstart2<<<gn, TPB, 0, stream>>>(degS, bsum, n, deg, row_start, dinv, x, ysA);
    k_fill_xcd <<<NTEAM*TEAMS_PER, TPB, 0, stream>>>(src, dst, E, n, degS, csr);

    k_gA    <<<gn4, TPB, 0, stream>>>(csr, row_start, deg, dinv, ysA, w11, b11, y4, n);
    k_gB    <<<gn4, TPB, 0, stream>>>(csr, row_start, deg, dinv, y4, w12, b12, w13, ysB, n);
    k_gC_mid<<<gn4, TPB, 0, stream>>>(csr, row_start, deg, dinv, ysB, b13, x2, ysA, n);
    k_gA    <<<gn4, TPB, 0, stream>>>(csr, row_start, deg, dinv, ysA, w21, b21, y4, n);
    k_gB    <<<gn4, TPB, 0, stream>>>(csr, row_start, deg, dinv, y4, w22, b22, w23, ysB, n);
    k_gC_fin<<<gn4, TPB, 0, stream>>>(csr, row_start, deg, dinv, ysB, b23, x2, out, pbuf, n);
    k_reduce_mean<<<1, 1024, 0, stream>>>(pbuf, gn4, out, 1.f/(float)n);
  }
}

// Round 7
// 406.173 us; speedup vs baseline: 10.1880x; 1.2324x over previous
//
#include <hip/hip_runtime.h>
#include <hip/hip_bf16.h>

#define TPB 256
#define NB 512          // partition buckets
#define MAXW 256        // max nodes per bucket (width = ceil(n/NB) must be <= MAXW)
#define P1K 16          // edges per thread per chunk; CH = TPB*P1K = 4096
#define NSHADOW 8       // fallback path
#define NTEAM 8
#define TEAMS_PER 256

// ============================ bucketed CSR build (deterministic offsets) ============================

// per-chunk 512-bin histogram of dst buckets; chunk c covers [c*CH, (c+1)*CH)
__global__ void k_bcount(const int* __restrict__ dst, int E, int n, int nchunk,
                         int* __restrict__ bhist){
  __shared__ int lh[NB];
  const int CH = TPB * P1K;
  for(int c = blockIdx.x; c < nchunk; c += gridDim.x){
    lh[threadIdx.x] = 0; lh[threadIdx.x + 256] = 0;
    __syncthreads();
    int cb = c * CH;
    #pragma unroll 4
    for(int i = 0; i < P1K; i++){
      int e = cb + i*TPB + threadIdx.x;
      if(e < E){
        int b = (int)(((long long)dst[e] * NB) / n);
        atomicAdd(&lh[b], 1);
      }
    }
    __syncthreads();
    bhist[(size_t)c*NB + threadIdx.x]       = lh[threadIdx.x];
    bhist[(size_t)c*NB + threadIdx.x + 256] = lh[threadIdx.x + 256];
    __syncthreads();
  }
}

// per-bucket totals: column sum of bhist
__global__ void k_btot(const int* __restrict__ bhist, int nchunk, int* __restrict__ bsize){
  int b = blockIdx.x;
  int s = 0;
  for(int c = threadIdx.x; c < nchunk; c += TPB) s += bhist[(size_t)c*NB + b];
  #pragma unroll
  for(int m=32; m; m>>=1) s += __shfl_xor(s, m, 64);
  __shared__ int ls[4];
  int lane = threadIdx.x & 63, w = threadIdx.x >> 6;
  if(lane == 0) ls[w] = s;
  __syncthreads();
  if(threadIdx.x == 0) bsize[b] = ls[0]+ls[1]+ls[2]+ls[3];
}

// single block: exclusive scan of bsize -> bucket_base
__global__ void k_bscan512(const int* __restrict__ bsize, int E, int* __restrict__ bucket_base){
  __shared__ int s[NB];
  int t = threadIdx.x;
  int v = bsize[t];
  s[t] = v;
  __syncthreads();
  for(int off = 1; off < NB; off <<= 1){
    int add = (t >= off) ? s[t-off] : 0;
    __syncthreads();
    s[t] += add;
    __syncthreads();
  }
  bucket_base[t] = s[t] - v;   // exclusive
  if(t == 0) bucket_base[NB] = E;
}

// in-place: bhist[c][b] (count) -> absolute base = bucket_base[b] + prefix_{c'<c} count
__global__ void k_offsets(int* __restrict__ bhist, const int* __restrict__ bucket_base,
                          int nchunk){
  __shared__ int s[TPB];
  int b = blockIdx.x;
  int run = bucket_base[b];
  for(int t0 = 0; t0 < nchunk; t0 += TPB){
    int c = t0 + threadIdx.x;
    int v = (c < nchunk) ? bhist[(size_t)c*NB + b] : 0;
    s[threadIdx.x] = v;
    __syncthreads();
    for(int off = 1; off < TPB; off <<= 1){
      int add = (threadIdx.x >= off) ? s[threadIdx.x - off] : 0;
      __syncthreads();
      s[threadIdx.x] += add;
      __syncthreads();
    }
    if(c < nchunk) bhist[(size_t)c*NB + b] = run + (s[threadIdx.x] - v);
    int tot = s[TPB-1];
    __syncthreads();
    run += tot;
  }
}

// single pass: scatter edges into dst-bucket-ordered temp as packed (src | dstLocal<<sbits)
__global__ void k_phase1(const int* __restrict__ src, const int* __restrict__ dst,
                         int E, int n, int nchunk, const int* __restrict__ lbase_g,
                         unsigned* __restrict__ temp, int sbits){
  __shared__ int lrank[NB], lbase[NB];
  const int CH = TPB * P1K;
  for(int c = blockIdx.x; c < nchunk; c += gridDim.x){
    lrank[threadIdx.x] = 0;        lrank[threadIdx.x + 256] = 0;
    lbase[threadIdx.x]       = lbase_g[(size_t)c*NB + threadIdx.x];
    lbase[threadIdx.x + 256] = lbase_g[(size_t)c*NB + threadIdx.x + 256];
    __syncthreads();
    int cb = c * CH;
    #pragma unroll 4
    for(int i = 0; i < P1K; i++){
      int e = cb + i*TPB + threadIdx.x;
      if(e < E){
        int d = dst[e];
        int b = (int)(((long long)d * NB) / n);
        int lo = (int)(((long long)n * b + NB - 1) / NB);
        int r = atomicAdd(&lrank[b], 1);
        temp[lbase[b] + r] = (unsigned)src[e] | ((unsigned)(d - lo) << sbits);
      }
    }
    __syncthreads();
  }
}

// per bucket (1 block): LDS degree histogram + scan -> deg,row_start,dinv,ysA. No global atomics.
__global__ void k_ldeg_scan(const unsigned* __restrict__ temp, const int* __restrict__ bucket_base,
                            int n, int sbits,
                            int* __restrict__ deg, int* __restrict__ row_start,
                            float* __restrict__ dinv,
                            const float* __restrict__ x, float* __restrict__ ysA){
  __shared__ int hist[MAXW], s[MAXW];
  int b = blockIdx.x;
  int lo = (int)(((long long)n * b + NB - 1) / NB);
  int hi = (int)(((long long)n * (b+1) + NB - 1) / NB);
  if(hi > n) hi = n;
  int width = hi - lo;
  int t = threadIdx.x;
  hist[t] = 0;
  __syncthreads();
  int e0 = bucket_base[b], e1 = bucket_base[b+1];
  for(int idx = e0 + t; idx < e1; idx += TPB)
    atomicAdd(&hist[temp[idx] >> sbits], 1);
  __syncthreads();
  int v = hist[t];
  s[t] = v;
  __syncthreads();
  for(int off = 1; off < MAXW; off <<= 1){
    int add = (t >= off) ? s[t-off] : 0;
    __syncthreads();
    s[t] += add;
    __syncthreads();
  }
  if(t < width){
    int node = lo + t;
    deg[node]       = v;
    row_start[node] = e0 + s[t] - v;
    float dv = rsqrtf((float)(v + 1));   // +1 self loop
    dinv[node] = dv;
    ysA[node]  = dv * (10.f * x[node]);
  }
}

// per bucket (1 block): scatter packed entries into exact csr slots via LDS cursors
__global__ void k_phase2(const unsigned* __restrict__ temp, const int* __restrict__ bucket_base,
                         const int* __restrict__ row_start, int n, int sbits, unsigned smask,
                         int* __restrict__ csr){
  __shared__ int cur[MAXW];
  int b = blockIdx.x;
  int lo = (int)(((long long)n * b + NB - 1) / NB);
  int hi = (int)(((long long)n * (b+1) + NB - 1) / NB);
  if(hi > n) hi = n;
  int width = hi - lo;
  if(threadIdx.x < width) cur[threadIdx.x] = row_start[lo + threadIdx.x];
  __syncthreads();
  int e0 = bucket_base[b], e1 = bucket_base[b+1];
  for(int idx = e0 + threadIdx.x; idx < e1; idx += TPB){
    unsigned u = temp[idx];
    int pos = atomicAdd(&cur[u >> sbits], 1);
    csr[pos] = (int)(u & smask);
  }
}

// ============================ fused gather layers ============================
// wave (64 lanes) per node; 4 nodes per 256-block

__global__ void k_gA(const int* __restrict__ csr, const int* __restrict__ row_start,
                     const int* __restrict__ deg, const float* __restrict__ dinv,
                     const float* __restrict__ ys, const float* __restrict__ W,
                     const float* __restrict__ B, float* __restrict__ y4, int n){
  int node = blockIdx.x*4 + (threadIdx.x >> 6);
  int lane = threadIdx.x & 63;
  if(node >= n) return;
  int rs = row_start[node], dg = deg[node];
  float s = 0.f;
  for(int j=lane; j<dg; j+=64) s += ys[csr[rs+j]];
  #pragma unroll
  for(int m=32; m; m>>=1) s += __shfl_xor(s, m, 64);
  if(lane == 0){
    float dv = dinv[node];
    float t  = dv * (ys[node] + s);
    float h0 = fmaxf(t*W[0]+B[0], 0.f);
    float h1 = fmaxf(t*W[1]+B[1], 0.f);
    float h2 = fmaxf(t*W[2]+B[2], 0.f);
    float h3 = fmaxf(t*W[3]+B[3], 0.f);
    *reinterpret_cast<float4*>(y4 + 4*(size_t)node) = make_float4(dv*h0, dv*h1, dv*h2, dv*h3);
  }
}

__global__ void k_gB(const int* __restrict__ csr, const int* __restrict__ row_start,
                     const int* __restrict__ deg, const float* __restrict__ dinv,
                     const float* __restrict__ y4, const float* __restrict__ W2,
                     const float* __restrict__ B2, const float* __restrict__ W3,
                     float* __restrict__ ys_out, int n){
  int node = blockIdx.x*4 + (threadIdx.x >> 6);
  int lane = threadIdx.x & 63;
  if(node >= n) return;
  int rs = row_start[node], dg = deg[node];
  float ax=0.f, ay=0.f, az=0.f, aw=0.f;
  for(int j=lane; j<dg; j+=64){
    float4 v = *reinterpret_cast<const float4*>(y4 + 4*(size_t)csr[rs+j]);
    ax += v.x; ay += v.y; az += v.z; aw += v.w;
  }
  #pragma unroll
  for(int m=32; m; m>>=1){
    ax += __shfl_xor(ax, m, 64);
    ay += __shfl_xor(ay, m, 64);
    az += __shfl_xor(az, m, 64);
    aw += __shfl_xor(aw, m, 64);
  }
  if(lane == 0){
    float dv = dinv[node];
    float4 sf = *reinterpret_cast<const float4*>(y4 + 4*(size_t)node);
    float z0 = dv*(ax+sf.x), z1 = dv*(ay+sf.y), z2 = dv*(az+sf.z), z3 = dv*(aw+sf.w);
    float s = 0.f;
    #pragma unroll
    for(int k=0;k<4;k++){
      float g = B2[k] + z0*W2[0*4+k] + z1*W2[1*4+k] + z2*W2[2*4+k] + z3*W2[3*4+k];
      g = fmaxf(g, 0.f);
      s += g * W3[k];
    }
    ys_out[node] = dv * s;
  }
}

__global__ void k_gC_mid(const int* __restrict__ csr, const int* __restrict__ row_start,
                         const int* __restrict__ deg, const float* __restrict__ dinv,
                         const float* __restrict__ ys, const float* __restrict__ B3,
                         float* __restrict__ x2, float* __restrict__ ys_out, int n){
  int node = blockIdx.x*4 + (threadIdx.x >> 6);
  int lane = threadIdx.x & 63;
  if(node >= n) return;
  int rs = row_start[node], dg = deg[node];
  float s = 0.f;
  for(int j=lane; j<dg; j+=64) s += ys[csr[rs+j]];
  #pragma unroll
  for(int m=32; m; m>>=1) s += __shfl_xor(s, m, 64);
  if(lane == 0){
    float dv = dinv[node];
    float u  = dv * (ys[node] + s) + B3[0];
    float v2 = sinf(10.f * u);
    x2[node] = v2;
    ys_out[node] = dv * v2;
  }
}

__global__ void k_gC_fin(const int* __restrict__ csr, const int* __restrict__ row_start,
                         const int* __restrict__ deg, const float* __restrict__ dinv,
                         const float* __restrict__ ys, const float* __restrict__ B3,
                         const float* __restrict__ x2, float* __restrict__ out,
                         float* __restrict__ pbuf, int n){
  int node = blockIdx.x*4 + (threadIdx.x >> 6);
  int lane = threadIdx.x & 63;
  int w = threadIdx.x >> 6;
  bool act = node < n;
  float v2 = 0.f, x3 = 0.f;
  if(act){
    int rs = row_start[node], dg = deg[node];
    float s = 0.f;
    for(int j=lane; j<dg; j+=64) s += ys[csr[rs+j]];
    #pragma unroll
    for(int m=32; m; m>>=1) s += __shfl_xor(s, m, 64);
    x3 = dinv[node] * (ys[node] + s) + B3[0];
    v2 = x2[node];
  }
  __shared__ float p2[4], p3[4];
  if(lane == 0){
    p2[w] = act ? v2 : 0.f;
    p3[w] = act ? x3 : 0.f;
    if(act)
      *reinterpret_cast<float2*>(out + 2 + 2*(size_t)node) = make_float2(v2, x3);
  }
  __syncthreads();
  if(threadIdx.x == 0){
    pbuf[2*(size_t)blockIdx.x]   = p2[0]+p2[1]+p2[2]+p2[3];
    pbuf[2*(size_t)blockIdx.x+1] = p3[0]+p3[1]+p3[2]+p3[3];
  }
}

__global__ void k_reduce_mean(const float* __restrict__ pbuf, int nb,
                              float* __restrict__ out, float invn){
  float s2 = 0.f, s3 = 0.f;
  for(int i = threadIdx.x; i < nb; i += 1024){
    s2 += pbuf[2*i];
    s3 += pbuf[2*i+1];
  }
  #pragma unroll
  for(int m=32; m; m>>=1){ s2 += __shfl_xor(s2, m, 64); s3 += __shfl_xor(s3, m, 64); }
  __shared__ float a2[16], a3[16];
  int w = threadIdx.x >> 6, lane = threadIdx.x & 63;
  if(lane == 0){ a2[w] = s2; a3[w] = s3; }
  __syncthreads();
  if(threadIdx.x == 0){
    float t2 = 0.f, t3 = 0.f;
    #pragma unroll
    for(int k=0;k<16;k++){ t2 += a2[k]; t3 += a3[k]; }
    out[0] = t2 * invn;
    out[1] = t3 * invn;
  }
}

// ============================ fallback build (round-5: shadowed deg + XCD fill) ============================

__global__ void k_zero8(int* __restrict__ degS, int m){
  int i = blockIdx.x*TPB + threadIdx.x;
  if(i < m) degS[i] = 0;
}

__global__ void k_deg8(const int* __restrict__ dst, int E, int* __restrict__ degS, int n){
  int e = blockIdx.x*TPB + threadIdx.x;
  if(e < E) atomicAdd(&degS[(size_t)(blockIdx.x & (NSHADOW-1))*(size_t)n + dst[e]], 1);
}

__global__ void k_bsum(const int* __restrict__ degS, int n, int* __restrict__ bsum){
  int i = blockIdx.x*TPB + threadIdx.x;
  int v = 0;
  if(i < n){
    #pragma unroll
    for(int s=0;s<NSHADOW;s++) v += degS[(size_t)s*(size_t)n + i];
  }
  #pragma unroll
  for(int off=32; off; off>>=1) v += __shfl_down(v, off, 64);
  __shared__ int ls[4];
  int lane = threadIdx.x & 63, w = threadIdx.x >> 6;
  if(lane == 0) ls[w] = v;
  __syncthreads();
  if(threadIdx.x == 0) bsum[blockIdx.x] = ls[0]+ls[1]+ls[2]+ls[3];
}

__global__ void k_bscan(int* __restrict__ bsum, int nb){
  __shared__ int s[1024];
  int t = threadIdx.x;
  int v = (t < nb) ? bsum[t] : 0;
  s[t] = v;
  __syncthreads();
  for(int off=1; off<1024; off<<=1){
    int add = (t >= off) ? s[t-off] : 0;
    __syncthreads();
    s[t] += add;
    __syncthreads();
  }
  if(t < nb) bsum[t] = s[t] - v;
}

__global__ void k_rowstart2(int* __restrict__ degS, const int* __restrict__ bsum, int n,
                            int* __restrict__ deg, int* __restrict__ row_start,
                            float* __restrict__ dinv,
                            const float* __restrict__ x, float* __restrict__ ysA){
  __shared__ int s[TPB];
  int i = blockIdx.x*TPB + threadIdx.x;
  int t = threadIdx.x;
  int c[NSHADOW];
  int v = 0;
  if(i < n){
    #pragma unroll
    for(int sh=0;sh<NSHADOW;sh++){ c[sh] = degS[(size_t)sh*(size_t)n + i]; v += c[sh]; }
  }
  s[t] = v;
  __syncthreads();
  for(int off=1; off<TPB; off<<=1){
    int add = (t >= off) ? s[t-off] : 0;
    __syncthreads();
    s[t] += add;
    __syncthreads();
  }
  if(i < n){
    int rs = bsum[blockIdx.x] + s[t] - v;
    deg[i]       = v;
    row_start[i] = rs;
    float dv = rsqrtf((float)(v + 1));
    dinv[i] = dv;
    ysA[i]  = dv * (10.f * x[i]);
    int base = rs;
    #pragma unroll
    for(int sh=0;sh<NSHADOW;sh++){ degS[(size_t)sh*(size_t)n + i] = base; base += c[sh]; }
  }
}

__global__ void k_fill_xcd(const int* __restrict__ src, const int* __restrict__ dst,
                           int E, int n, int* __restrict__ cursorS, int* __restrict__ csr){
  int team = blockIdx.x & (NTEAM-1);
  int tr   = blockIdx.x >> 3;
  int lo = (int)(((long long)n * team) >> 3);
  int hi = (int)(((long long)n * (team+1)) >> 3);
  int nchunk = (E + TPB - 1) / TPB;
  for(int ci = tr; ci < nchunk; ci += TEAMS_PER){
    int e = ci*TPB + threadIdx.x;
    if(e < E){
      int d = dst[e];
      if(d >= lo && d < hi){
        int sh = ci & (NSHADOW-1);
        int pos = atomicAdd(&cursorS[(size_t)sh*(size_t)n + d], 1);
        csr[pos] = src[e];
      }
    }
  }
}

// ============================ launch ============================

extern "C" void kernel_launch(void* const* d_in, const int* in_sizes, int n_in,
                              void* d_out, int out_size, void* d_ws, size_t ws_size,
                              hipStream_t stream) {
  const float* x   = (const float*)d_in[0];
  const int*   ei  = (const int*)  d_in[1];
  const float* w11 = (const float*)d_in[2];
  const float* b11 = (const float*)d_in[3];
  const float* w12 = (const float*)d_in[4];
  const float* b12 = (const float*)d_in[5];
  const float* w13 = (const float*)d_in[6];
  const float* b13 = (const float*)d_in[7];
  const float* w21 = (const float*)d_in[8];
  const float* b21 = (const float*)d_in[9];
  const float* w22 = (const float*)d_in[10];
  const float* b22 = (const float*)d_in[11];
  const float* w23 = (const float*)d_in[12];
  const float* b23 = (const float*)d_in[13];
  float* out = (float*)d_out;

  const int n = in_sizes[0];
  const int E = in_sizes[1] / 2;
  const int* src = ei;
  const int* dst = ei + E;

  const int gn  = (n + TPB - 1)/TPB;
  const int gn4 = (n + 3)/4;
  const int ge  = (E + TPB - 1)/TPB;

  float* ws = (float*)d_ws;

  // packing parameters for bucket path
  int sbits = 1; while((1 << sbits) < n && sbits < 31) sbits++;          // bits for src
  int maxw  = (n + NB - 1) / NB;
  int dbits = 1; while((1 << dbits) < maxw && dbits < 31) dbits++;       // bits for dstLocal
  unsigned smask = (sbits >= 31) ? 0x7FFFFFFFu : ((1u << sbits) - 1u);

  const int CH = TPB * P1K;
  const int nchunk = (E + CH - 1) / CH;

  const size_t need_bucket = ((size_t)10*n + 1536 + (size_t)(nchunk+1)*NB + 2*(size_t)E + 64) * 4;
  const size_t need_r5     = ((size_t)18*n + 1024 + (size_t)E) * 4;

  if(ws_size >= need_bucket && n >= NB && maxw <= MAXW && (sbits + dbits) <= 32){
    // ---------------- deterministic bucketed-build CSR path ----------------
    float*    y4          = ws;                               // 4n (pbuf alias later)
    float*    dinv        = ws + 4*(size_t)n;                 // n
    float*    ysA         = ws + 5*(size_t)n;                 // n
    float*    ysB         = ws + 6*(size_t)n;                 // n
    float*    x2          = ws + 7*(size_t)n;                 // n
    int*      deg         = (int*)(ws + 8*(size_t)n);         // n
    int*      row_start   = (int*)(ws + 9*(size_t)n);         // n
    int*      bucket_base = (int*)(ws + 10*(size_t)n);        // NB+1 (pad 1024)
    int*      bsize       = bucket_base + 1024;               // NB (pad 512)
    int*      bhist       = bsize + 512;                      // nchunk*NB
    unsigned* temp        = (unsigned*)(bhist + (size_t)nchunk*NB);  // E
    int*      csr         = (int*)(temp + (size_t)E);         // E
    float*    pbuf        = y4;

    int gbuild = nchunk < 8192 ? nchunk : 8192;
    k_bcount  <<<gbuild, TPB, 0, stream>>>(dst, E, n, nchunk, bhist);
    k_btot    <<<NB, TPB, 0, stream>>>(bhist, nchunk, bsize);
    k_bscan512<<<1, NB, 0, stream>>>(bsize, E, bucket_base);
    k_offsets <<<NB, TPB, 0, stream>>>(bhist, bucket_base, nchunk);
    k_phase1  <<<gbuild, TPB, 0, stream>>>(src, dst, E, n, nchunk, bhist, temp, sbits);
    k_ldeg_scan<<<NB, TPB, 0, stream>>>(temp, bucket_base, n, sbits, deg, row_start, dinv, x, ysA);
    k_phase2  <<<NB, TPB, 0, stream>>>(temp, bucket_base, row_start, n, sbits, smask, csr);

    // gcn #1
    k_gA    <<<gn4, TPB, 0, stream>>>(csr, row_start, deg, dinv, ysA, w11, b11, y4, n);
    k_gB    <<<gn4, TPB, 0, stream>>>(csr, row_start, deg, dinv, y4, w12, b12, w13, ysB, n);
    k_gC_mid<<<gn4, TPB, 0, stream>>>(csr, row_start, deg, dinv, ysB, b13, x2, ysA, n);
    // gcn #2
    k_gA    <<<gn4, TPB, 0, stream>>>(csr, row_start, deg, dinv, ysA, w21, b21, y4, n);
    k_gB    <<<gn4, TPB, 0, stream>>>(csr, row_start, deg, dinv, y4, w22, b22, w23, ysB, n);
    k_gC_fin<<<gn4, TPB, 0, stream>>>(csr, row_start, deg, dinv, ysB, b23, x2, out, pbuf, n);
    k_reduce_mean<<<1, 1024, 0, stream>>>(pbuf, gn4, out, 1.f/(float)n);
  } else if(ws_size >= need_r5 && gn <= 1024 && (size_t)E >= (size_t)NSHADOW*(size_t)n){
    // ---------------- round-5 CSR path (fallback) ----------------
    float* y4        = ws;
    float* dinv      = ws + 4*(size_t)n;
    float* ysA       = ws + 5*(size_t)n;
    float* ysB       = ws + 6*(size_t)n;
    float* x2        = ws + 7*(size_t)n;
    int*   deg       = (int*)(ws + 8*(size_t)n);
    int*   row_start = (int*)(ws + 9*(size_t)n);
    int*   bsum      = (int*)(ws + 10*(size_t)n);
    int*   degS      = (int*)(ws + 10*(size_t)n + 1024);
    int*   csr       = degS + 8*(size_t)n;
    float* pbuf      = y4;

    const int m8 = NSHADOW*n;
    k_zero8    <<<(m8+TPB-1)/TPB, TPB, 0, stream>>>(degS, m8);
    k_deg8     <<<ge, TPB, 0, stream>>>(dst, E, degS, n);
    k_bsum     <<<gn, TPB, 0, stream>>>(degS, n, bsum);
    k_bscan    <<<1, 1024, 0, stream>>>(bsum, gn);
    k_rowstart2<<<gn, TPB, 0, stream>>>(degS, bsum, n, deg, row_start, dinv, x, ysA);
    k_fill_xcd <<<NTEAM*TEAMS_PER, TPB, 0, stream>>>(src, dst, E, n, degS, csr);

    k_gA    <<<gn4, TPB, 0, stream>>>(csr, row_start, deg, dinv, ysA, w11, b11, y4, n);
    k_gB    <<<gn4, TPB, 0, stream>>>(csr, row_start, deg, dinv, y4, w12, b12, w13, ysB, n);
    k_gC_mid<<<gn4, TPB, 0, stream>>>(csr, row_start, deg, dinv, ysB, b13, x2, ysA, n);
    k_gA    <<<gn4, TPB, 0, stream>>>(csr, row_start, deg, dinv, ysA, w21, b21, y4, n);
    k_gB    <<<gn4, TPB, 0, stream>>>(csr, row_start, deg, dinv, y4, w22, b22, w23, ysB, n);
    k_gC_fin<<<gn4, TPB, 0, stream>>>(csr, row_start, deg, dinv, ysB, b23, x2, out, pbuf, n);
    k_reduce_mean<<<1, 1024, 0, stream>>>(pbuf, gn4, out, 1.f/(float)n);
  }
}

// Round 8
// 400.079 us; speedup vs baseline: 10.3432x; 1.0152x over previous
//
#include <hip/hip_runtime.h>
#include <hip/hip_bf16.h>

#define TPB 256
#define NB 512          // partition buckets
#define MAXW 256        // max nodes per bucket (width = ceil(n/NB) must be <= MAXW)
#define P1K 32          // edges per thread per chunk; CH = TPB*P1K = 8192 (64B runs per bucket)
#define NSHADOW 8       // fallback path
#define NTEAM 8
#define TEAMS_PER 256

// ============================ bucketed CSR build (deterministic offsets) ============================

// per-chunk 512-bin histogram of dst buckets; chunk c covers [c*CH, (c+1)*CH)
__global__ void k_bcount(const int* __restrict__ dst, int E, int n, int nchunk,
                         int* __restrict__ bhist){
  __shared__ int lh[NB];
  const int CH = TPB * P1K;
  for(int c = blockIdx.x; c < nchunk; c += gridDim.x){
    lh[threadIdx.x] = 0; lh[threadIdx.x + 256] = 0;
    __syncthreads();
    int cb = c * CH;
    #pragma unroll 4
    for(int i = 0; i < P1K; i++){
      int e = cb + i*TPB + threadIdx.x;
      if(e < E){
        int b = (int)(((long long)dst[e] * NB) / n);
        atomicAdd(&lh[b], 1);
      }
    }
    __syncthreads();
    bhist[(size_t)c*NB + threadIdx.x]       = lh[threadIdx.x];
    bhist[(size_t)c*NB + threadIdx.x + 256] = lh[threadIdx.x + 256];
    __syncthreads();
  }
}

// per-bucket totals: column sum of bhist
__global__ void k_btot(const int* __restrict__ bhist, int nchunk, int* __restrict__ bsize){
  int b = blockIdx.x;
  int s = 0;
  for(int c = threadIdx.x; c < nchunk; c += TPB) s += bhist[(size_t)c*NB + b];
  #pragma unroll
  for(int m=32; m; m>>=1) s += __shfl_xor(s, m, 64);
  __shared__ int ls[4];
  int lane = threadIdx.x & 63, w = threadIdx.x >> 6;
  if(lane == 0) ls[w] = s;
  __syncthreads();
  if(threadIdx.x == 0) bsize[b] = ls[0]+ls[1]+ls[2]+ls[3];
}

// single block: exclusive scan of bsize -> bucket_base
__global__ void k_bscan512(const int* __restrict__ bsize, int E, int* __restrict__ bucket_base){
  __shared__ int s[NB];
  int t = threadIdx.x;
  int v = bsize[t];
  s[t] = v;
  __syncthreads();
  for(int off = 1; off < NB; off <<= 1){
    int add = (t >= off) ? s[t-off] : 0;
    __syncthreads();
    s[t] += add;
    __syncthreads();
  }
  bucket_base[t] = s[t] - v;   // exclusive
  if(t == 0) bucket_base[NB] = E;
}

// in-place: bhist[c][b] (count) -> absolute base = bucket_base[b] + prefix_{c'<c} count
__global__ void k_offsets(int* __restrict__ bhist, const int* __restrict__ bucket_base,
                          int nchunk){
  __shared__ int s[TPB];
  int b = blockIdx.x;
  int run = bucket_base[b];
  for(int t0 = 0; t0 < nchunk; t0 += TPB){
    int c = t0 + threadIdx.x;
    int v = (c < nchunk) ? bhist[(size_t)c*NB + b] : 0;
    s[threadIdx.x] = v;
    __syncthreads();
    for(int off = 1; off < TPB; off <<= 1){
      int add = (threadIdx.x >= off) ? s[threadIdx.x - off] : 0;
      __syncthreads();
      s[threadIdx.x] += add;
      __syncthreads();
    }
    if(c < nchunk) bhist[(size_t)c*NB + b] = run + (s[threadIdx.x] - v);
    int tot = s[TPB-1];
    __syncthreads();
    run += tot;
  }
}

// single pass: scatter edges into dst-bucket-ordered temp as packed (src | dstLocal<<sbits)
__global__ void k_phase1(const int* __restrict__ src, const int* __restrict__ dst,
                         int E, int n, int nchunk, const int* __restrict__ lbase_g,
                         unsigned* __restrict__ temp, int sbits){
  __shared__ int lrank[NB], lbase[NB];
  const int CH = TPB * P1K;
  for(int c = blockIdx.x; c < nchunk; c += gridDim.x){
    lrank[threadIdx.x] = 0;        lrank[threadIdx.x + 256] = 0;
    lbase[threadIdx.x]       = lbase_g[(size_t)c*NB + threadIdx.x];
    lbase[threadIdx.x + 256] = lbase_g[(size_t)c*NB + threadIdx.x + 256];
    __syncthreads();
    int cb = c * CH;
    #pragma unroll 4
    for(int i = 0; i < P1K; i++){
      int e = cb + i*TPB + threadIdx.x;
      if(e < E){
        int d = dst[e];
        int b = (int)(((long long)d * NB) / n);
        int lo = (int)(((long long)n * b + NB - 1) / NB);
        int r = atomicAdd(&lrank[b], 1);
        temp[lbase[b] + r] = (unsigned)src[e] | ((unsigned)(d - lo) << sbits);
      }
    }
    __syncthreads();
  }
}

// per bucket (1 block): LDS degree histogram + scan -> deg,row_start,dinv,ysA,
// then scatter packed entries into exact csr slots via LDS cursors (fused former phase2).
__global__ void k_bucket_build(const unsigned* __restrict__ temp, const int* __restrict__ bucket_base,
                               int n, int sbits, unsigned smask,
                               int* __restrict__ deg, int* __restrict__ row_start,
                               float* __restrict__ dinv,
                               const float* __restrict__ x, float* __restrict__ ysA,
                               int* __restrict__ csr){
  __shared__ int hist[MAXW], s[MAXW], cur[MAXW];
  int b = blockIdx.x;
  int lo = (int)(((long long)n * b + NB - 1) / NB);
  int hi = (int)(((long long)n * (b+1) + NB - 1) / NB);
  if(hi > n) hi = n;
  int width = hi - lo;
  int t = threadIdx.x;
  hist[t] = 0;
  __syncthreads();
  int e0 = bucket_base[b], e1 = bucket_base[b+1];
  for(int idx = e0 + t; idx < e1; idx += TPB)
    atomicAdd(&hist[temp[idx] >> sbits], 1);
  __syncthreads();
  int v = hist[t];
  s[t] = v;
  __syncthreads();
  for(int off = 1; off < MAXW; off <<= 1){
    int add = (t >= off) ? s[t-off] : 0;
    __syncthreads();
    s[t] += add;
    __syncthreads();
  }
  int rs = e0 + s[t] - v;
  cur[t] = rs;
  if(t < width){
    int node = lo + t;
    deg[node]       = v;
    row_start[node] = rs;
    float dv = rsqrtf((float)(v + 1));   // +1 self loop
    dinv[node] = dv;
    ysA[node]  = dv * (10.f * x[node]);
  }
  __syncthreads();
  for(int idx = e0 + t; idx < e1; idx += TPB){
    unsigned u = temp[idx];
    int pos = atomicAdd(&cur[u >> sbits], 1);
    csr[pos] = (int)(u & smask);
  }
}

// ============================ fused gather layers ============================
// wave (64 lanes) per node; 4 nodes per 256-block

__global__ void k_gA(const int* __restrict__ csr, const int* __restrict__ row_start,
                     const int* __restrict__ deg, const float* __restrict__ dinv,
                     const float* __restrict__ ys, const float* __restrict__ W,
                     const float* __restrict__ B, float* __restrict__ y4, int n){
  int node = blockIdx.x*4 + (threadIdx.x >> 6);
  int lane = threadIdx.x & 63;
  if(node >= n) return;
  int rs = row_start[node], dg = deg[node];
  float s = 0.f;
  for(int j=lane; j<dg; j+=64) s += ys[csr[rs+j]];
  #pragma unroll
  for(int m=32; m; m>>=1) s += __shfl_xor(s, m, 64);
  if(lane == 0){
    float dv = dinv[node];
    float t  = dv * (ys[node] + s);
    float h0 = fmaxf(t*W[0]+B[0], 0.f);
    float h1 = fmaxf(t*W[1]+B[1], 0.f);
    float h2 = fmaxf(t*W[2]+B[2], 0.f);
    float h3 = fmaxf(t*W[3]+B[3], 0.f);
    *reinterpret_cast<float4*>(y4 + 4*(size_t)node) = make_float4(dv*h0, dv*h1, dv*h2, dv*h3);
  }
}

__global__ void k_gB(const int* __restrict__ csr, const int* __restrict__ row_start,
                     const int* __restrict__ deg, const float* __restrict__ dinv,
                     const float* __restrict__ y4, const float* __restrict__ W2,
                     const float* __restrict__ B2, const float* __restrict__ W3,
                     float* __restrict__ ys_out, int n){
  int node = blockIdx.x*4 + (threadIdx.x >> 6);
  int lane = threadIdx.x & 63;
  if(node >= n) return;
  int rs = row_start[node], dg = deg[node];
  float ax=0.f, ay=0.f, az=0.f, aw=0.f;
  for(int j=lane; j<dg; j+=64){
    float4 v = *reinterpret_cast<const float4*>(y4 + 4*(size_t)csr[rs+j]);
    ax += v.x; ay += v.y; az += v.z; aw += v.w;
  }
  #pragma unroll
  for(int m=32; m; m>>=1){
    ax += __shfl_xor(ax, m, 64);
    ay += __shfl_xor(ay, m, 64);
    az += __shfl_xor(az, m, 64);
    aw += __shfl_xor(aw, m, 64);
  }
  if(lane == 0){
    float dv = dinv[node];
    float4 sf = *reinterpret_cast<const float4*>(y4 + 4*(size_t)node);
    float z0 = dv*(ax+sf.x), z1 = dv*(ay+sf.y), z2 = dv*(az+sf.z), z3 = dv*(aw+sf.w);
    float s = 0.f;
    #pragma unroll
    for(int k=0;k<4;k++){
      float g = B2[k] + z0*W2[0*4+k] + z1*W2[1*4+k] + z2*W2[2*4+k] + z3*W2[3*4+k];
      g = fmaxf(g, 0.f);
      s += g * W3[k];
    }
    ys_out[node] = dv * s;
  }
}

__global__ void k_gC_mid(const int* __restrict__ csr, const int* __restrict__ row_start,
                         const int* __restrict__ deg, const float* __restrict__ dinv,
                         const float* __restrict__ ys, const float* __restrict__ B3,
                         float* __restrict__ x2, float* __restrict__ ys_out, int n){
  int node = blockIdx.x*4 + (threadIdx.x >> 6);
  int lane = threadIdx.x & 63;
  if(node >= n) return;
  int rs = row_start[node], dg = deg[node];
  float s = 0.f;
  for(int j=lane; j<dg; j+=64) s += ys[csr[rs+j]];
  #pragma unroll
  for(int m=32; m; m>>=1) s += __shfl_xor(s, m, 64);
  if(lane == 0){
    float dv = dinv[node];
    float u  = dv * (ys[node] + s) + B3[0];
    float v2 = sinf(10.f * u);
    x2[node] = v2;
    ys_out[node] = dv * v2;
  }
}

__global__ void k_gC_fin(const int* __restrict__ csr, const int* __restrict__ row_start,
                         const int* __restrict__ deg, const float* __restrict__ dinv,
                         const float* __restrict__ ys, const float* __restrict__ B3,
                         const float* __restrict__ x2, float* __restrict__ out,
                         float* __restrict__ pbuf, int n){
  int node = blockIdx.x*4 + (threadIdx.x >> 6);
  int lane = threadIdx.x & 63;
  int w = threadIdx.x >> 6;
  bool act = node < n;
  float v2 = 0.f, x3 = 0.f;
  if(act){
    int rs = row_start[node], dg = deg[node];
    float s = 0.f;
    for(int j=lane; j<dg; j+=64) s += ys[csr[rs+j]];
    #pragma unroll
    for(int m=32; m; m>>=1) s += __shfl_xor(s, m, 64);
    x3 = dinv[node] * (ys[node] + s) + B3[0];
    v2 = x2[node];
  }
  __shared__ float p2[4], p3[4];
  if(lane == 0){
    p2[w] = act ? v2 : 0.f;
    p3[w] = act ? x3 : 0.f;
    if(act)
      *reinterpret_cast<float2*>(out + 2 + 2*(size_t)node) = make_float2(v2, x3);
  }
  __syncthreads();
  if(threadIdx.x == 0){
    pbuf[2*(size_t)blockIdx.x]   = p2[0]+p2[1]+p2[2]+p2[3];
    pbuf[2*(size_t)blockIdx.x+1] = p3[0]+p3[1]+p3[2]+p3[3];
  }
}

__global__ void k_reduce_mean(const float* __restrict__ pbuf, int nb,
                              float* __restrict__ out, float invn){
  float s2 = 0.f, s3 = 0.f;
  for(int i = threadIdx.x; i < nb; i += 1024){
    s2 += pbuf[2*i];
    s3 += pbuf[2*i+1];
  }
  #pragma unroll
  for(int m=32; m; m>>=1){ s2 += __shfl_xor(s2, m, 64); s3 += __shfl_xor(s3, m, 64); }
  __shared__ float a2[16], a3[16];
  int w = threadIdx.x >> 6, lane = threadIdx.x & 63;
  if(lane == 0){ a2[w] = s2; a3[w] = s3; }
  __syncthreads();
  if(threadIdx.x == 0){
    float t2 = 0.f, t3 = 0.f;
    #pragma unroll
    for(int k=0;k<16;k++){ t2 += a2[k]; t3 += a3[k]; }
    out[0] = t2 * invn;
    out[1] = t3 * invn;
  }
}

// ============================ fallback build (round-5: shadowed deg + XCD fill) ============================

__global__ void k_zero8(int* __restrict__ degS, int m){
  int i = blockIdx.x*TPB + threadIdx.x;
  if(i < m) degS[i] = 0;
}

__global__ void k_deg8(const int* __restrict__ dst, int E, int* __restrict__ degS, int n){
  int e = blockIdx.x*TPB + threadIdx.x;
  if(e < E) atomicAdd(&degS[(size_t)(blockIdx.x & (NSHADOW-1))*(size_t)n + dst[e]], 1);
}

__global__ void k_bsum(const int* __restrict__ degS, int n, int* __restrict__ bsum){
  int i = blockIdx.x*TPB + threadIdx.x;
  int v = 0;
  if(i < n){
    #pragma unroll
    for(int s=0;s<NSHADOW;s++) v += degS[(size_t)s*(size_t)n + i];
  }
  #pragma unroll
  for(int off=32; off; off>>=1) v += __shfl_down(v, off, 64);
  __shared__ int ls[4];
  int lane = threadIdx.x & 63, w = threadIdx.x >> 6;
  if(lane == 0) ls[w] = v;
  __syncthreads();
  if(threadIdx.x == 0) bsum[blockIdx.x] = ls[0]+ls[1]+ls[2]+ls[3];
}

__global__ void k_bscan(int* __restrict__ bsum, int nb){
  __shared__ int s[1024];
  int t = threadIdx.x;
  int v = (t < nb) ? bsum[t] : 0;
  s[t] = v;
  __syncthreads();
  for(int off=1; off<1024; off<<=1){
    int add = (t >= off) ? s[t-off] : 0;
    __syncthreads();
    s[t] += add;
    __syncthreads();
  }
  if(t < nb) bsum[t] = s[t] - v;
}

__global__ void k_rowstart2(int* __restrict__ degS, const int* __restrict__ bsum, int n,
                            int* __restrict__ deg, int* __restrict__ row_start,
                            float* __restrict__ dinv,
                            const float* __restrict__ x, float* __restrict__ ysA){
  __shared__ int s[TPB];
  int i = blockIdx.x*TPB + threadIdx.x;
  int t = threadIdx.x;
  int c[NSHADOW];
  int v = 0;
  if(i < n){
    #pragma unroll
    for(int sh=0;sh<NSHADOW;sh++){ c[sh] = degS[(size_t)sh*(size_t)n + i]; v += c[sh]; }
  }
  s[t] = v;
  __syncthreads();
  for(int off=1; off<TPB; off<<=1){
    int add = (t >= off) ? s[t-off] : 0;
    __syncthreads();
    s[t] += add;
    __syncthreads();
  }
  if(i < n){
    int rs = bsum[blockIdx.x] + s[t] - v;
    deg[i]       = v;
    row_start[i] = rs;
    float dv = rsqrtf((float)(v + 1));
    dinv[i] = dv;
    ysA[i]  = dv * (10.f * x[i]);
    int base = rs;
    #pragma unroll
    for(int sh=0;sh<NSHADOW;sh++){ degS[(size_t)sh*(size_t)n + i] = base; base += c[sh]; }
  }
}

__global__ void k_fill_xcd(const int* __restrict__ src, const int* __restrict__ dst,
                           int E, int n, int* __restrict__ cursorS, int* __restrict__ csr){
  int team = blockIdx.x & (NTEAM-1);
  int tr   = blockIdx.x >> 3;
  int lo = (int)(((long long)n * team) >> 3);
  int hi = (int)(((long long)n * (team+1)) >> 3);
  int nchunk = (E + TPB - 1) / TPB;
  for(int ci = tr; ci < nchunk; ci += TEAMS_PER){
    int e = ci*TPB + threadIdx.x;
    if(e < E){
      int d = dst[e];
      if(d >= lo && d < hi){
        int sh = ci & (NSHADOW-1);
        int pos = atomicAdd(&cursorS[(size_t)sh*(size_t)n + d], 1);
        csr[pos] = src[e];
      }
    }
  }
}

// ============================ launch ============================

extern "C" void kernel_launch(void* const* d_in, const int* in_sizes, int n_in,
                              void* d_out, int out_size, void* d_ws, size_t ws_size,
                              hipStream_t stream) {
  const float* x   = (const float*)d_in[0];
  const int*   ei  = (const int*)  d_in[1];
  const float* w11 = (const float*)d_in[2];
  const float* b11 = (const float*)d_in[3];
  const float* w12 = (const float*)d_in[4];
  const float* b12 = (const float*)d_in[5];
  const float* w13 = (const float*)d_in[6];
  const float* b13 = (const float*)d_in[7];
  const float* w21 = (const float*)d_in[8];
  const float* b21 = (const float*)d_in[9];
  const float* w22 = (const float*)d_in[10];
  const float* b22 = (const float*)d_in[11];
  const float* w23 = (const float*)d_in[12];
  const float* b23 = (const float*)d_in[13];
  float* out = (float*)d_out;

  const int n = in_sizes[0];
  const int E = in_sizes[1] / 2;
  const int* src = ei;
  const int* dst = ei + E;

  const int gn  = (n + TPB - 1)/TPB;
  const int gn4 = (n + 3)/4;
  const int ge  = (E + TPB - 1)/TPB;

  float* ws = (float*)d_ws;

  // packing parameters for bucket path
  int sbits = 1; while((1 << sbits) < n && sbits < 31) sbits++;          // bits for src
  int maxw  = (n + NB - 1) / NB;
  int dbits = 1; while((1 << dbits) < maxw && dbits < 31) dbits++;       // bits for dstLocal
  unsigned smask = (sbits >= 31) ? 0x7FFFFFFFu : ((1u << sbits) - 1u);

  const int CH = TPB * P1K;
  const int nchunk = (E + CH - 1) / CH;

  const size_t need_bucket = ((size_t)10*n + 1536 + (size_t)(nchunk+1)*NB + 2*(size_t)E + 64) * 4;
  const size_t need_r5     = ((size_t)18*n + 1024 + (size_t)E) * 4;

  if(ws_size >= need_bucket && n >= NB && maxw <= MAXW && (sbits + dbits) <= 32){
    // ---------------- deterministic bucketed-build CSR path ----------------
    float*    y4          = ws;                               // 4n (pbuf alias later)
    float*    dinv        = ws + 4*(size_t)n;                 // n
    float*    ysA         = ws + 5*(size_t)n;                 // n
    float*    ysB         = ws + 6*(size_t)n;                 // n
    float*    x2          = ws + 7*(size_t)n;                 // n
    int*      deg         = (int*)(ws + 8*(size_t)n);         // n
    int*      row_start   = (int*)(ws + 9*(size_t)n);         // n
    int*      bucket_base = (int*)(ws + 10*(size_t)n);        // NB+1 (pad 1024)
    int*      bsize       = bucket_base + 1024;               // NB (pad 512)
    int*      bhist       = bsize + 512;                      // nchunk*NB
    unsigned* temp        = (unsigned*)(bhist + (size_t)nchunk*NB);  // E
    int*      csr         = (int*)(temp + (size_t)E);         // E
    float*    pbuf        = y4;

    int gbuild = nchunk < 8192 ? nchunk : 8192;
    k_bcount  <<<gbuild, TPB, 0, stream>>>(dst, E, n, nchunk, bhist);
    k_btot    <<<NB, TPB, 0, stream>>>(bhist, nchunk, bsize);
    k_bscan512<<<1, NB, 0, stream>>>(bsize, E, bucket_base);
    k_offsets <<<NB, TPB, 0, stream>>>(bhist, bucket_base, nchunk);
    k_phase1  <<<gbuild, TPB, 0, stream>>>(src, dst, E, n, nchunk, bhist, temp, sbits);
    k_bucket_build<<<NB, TPB, 0, stream>>>(temp, bucket_base, n, sbits, smask,
                                           deg, row_start, dinv, x, ysA, csr);

    // gcn #1
    k_gA    <<<gn4, TPB, 0, stream>>>(csr, row_start, deg, dinv, ysA, w11, b11, y4, n);
    k_gB    <<<gn4, TPB, 0, stream>>>(csr, row_start, deg, dinv, y4, w12, b12, w13, ysB, n);
    k_gC_mid<<<gn4, TPB, 0, stream>>>(csr, row_start, deg, dinv, ysB, b13, x2, ysA, n);
    // gcn #2
    k_gA    <<<gn4, TPB, 0, stream>>>(csr, row_start, deg, dinv, ysA, w21, b21, y4, n);
    k_gB    <<<gn4, TPB, 0, stream>>>(csr, row_start, deg, dinv, y4, w22, b22, w23, ysB, n);
    k_gC_fin<<<gn4, TPB, 0, stream>>>(csr, row_start, deg, dinv, ysB, b23, x2, out, pbuf, n);
    k_reduce_mean<<<1, 1024, 0, stream>>>(pbuf, gn4, out, 1.f/(float)n);
  } else if(ws_size >= need_r5 && gn <= 1024 && (size_t)E >= (size_t)NSHADOW*(size_t)n){
    // ---------------- round-5 CSR path (fallback) ----------------
    float* y4        = ws;
    float* dinv      = ws + 4*(size_t)n;
    float* ysA       = ws + 5*(size_t)n;
    float* ysB       = ws + 6*(size_t)n;
    float* x2        = ws + 7*(size_t)n;
    int*   deg       = (int*)(ws + 8*(size_t)n);
    int*   row_start = (int*)(ws + 9*(size_t)n);
    int*   bsum      = (int*)(ws + 10*(size_t)n);
    int*   degS      = (int*)(ws + 10*(size_t)n + 1024);
    int*   csr       = degS + 8*(size_t)n;
    float* pbuf      = y4;

    const int m8 = NSHADOW*n;
    k_zero8    <<<(m8+TPB-1)/TPB, TPB, 0, stream>>>(degS, m8);
    k_deg8     <<<ge, TPB, 0, stream>>>(dst, E, degS, n);
    k_bsum     <<<gn, TPB, 0, stream>>>(degS, n, bsum);
    k_bscan    <<<1, 1024, 0, stream>>>(bsum, gn);
    k_rowstart2<<<gn, TPB, 0, stream>>>(degS, bsum, n, deg, row_start, dinv, x, ysA);
    k_fill_xcd <<<NTEAM*TEAMS_PER, TPB, 0, stream>>>(src, dst, E, n, degS, csr);

    k_gA    <<<gn4, TPB, 0, stream>>>(csr, row_start, deg, dinv, ysA, w11, b11, y4, n);
    k_gB    <<<gn4, TPB, 0, stream>>>(csr, row_start, deg, dinv, y4, w12, b12, w13, ysB, n);
    k_gC_mid<<<gn4, TPB, 0, stream>>>(csr, row_start, deg, dinv, ysB, b13, x2, ysA, n);
    k_gA    <<<gn4, TPB, 0, stream>>>(csr, row_start, deg, dinv, ysA, w21, b21, y4, n);
    k_gB    <<<gn4, TPB, 0, stream>>>(csr, row_start, deg, dinv, y4, w22, b22, w23, ysB, n);
    k_gC_fin<<<gn4, TPB, 0, stream>>>(csr, row_start, deg, dinv, ysB, b23, x2, out, pbuf, n);
    k_reduce_mean<<<1, 1024, 0, stream>>>(pbuf, gn4, out, 1.f/(float)n);
  }
}